// Round 1
// baseline (2970.980 us; speedup 1.0000x reference)
//
#include <hip/hip_runtime.h>
#include <math.h>

// Shapes: B=16, x[16,256,256,3], h1[16,128,128,128], h2[16,64,64,128],
// z_e/z_q[65536,64], g1[16,128,128,128], x_rec[16,256,256,3], K=1024 codes.

__device__ __forceinline__ float gelu_f(float x) {
    float x3 = x*x*x;
    return 0.5f*x*(1.0f + tanhf(0.7978845608028654f*(x + 0.044715f*x3)));
}

// ---------------- conv1: x[16,256,256,3] -> h1[16,128,128,128], 4x4 s2 SAME, GELU
// pad=1. block: (b, oy, ox-tile of 64). 256 thr: 16 cgroups x 8ch, 16 pgroups x 4px.
__global__ __launch_bounds__(256) void k_conv1(const float* __restrict__ x,
        const float* __restrict__ w, const float* __restrict__ bias,
        float* __restrict__ out) {
    __shared__ __align__(16) float ws[48*128];
    __shared__ __align__(16) float xs[4][390];   // 130 ix-positions x 3 ci
    const int tid = threadIdx.x;
    const int blk = blockIdx.x;
    const int oxt = blk & 1;
    const int oy  = (blk >> 1) & 127;
    const int b   = blk >> 8;
    const int cg = tid & 15, pg = tid >> 4;
    const int c0 = cg*8, p0 = pg*4;
    const int ox0 = oxt*64;

    for (int i = tid; i < 6144; i += 256) ws[i] = w[i];
    for (int r = 0; r < 4; ++r) {
        int iy = 2*oy + r - 1;
        bool yok = (unsigned)iy < 256u;
        const float* xrow = x + ((size_t)(b*256) + iy)*256*3;
        for (int i = tid; i < 390; i += 256) {
            int ixl = i/3, ci = i - ixl*3;
            int ix = 2*ox0 - 1 + ixl;
            xs[r][i] = (yok && (unsigned)ix < 256u) ? xrow[(size_t)ix*3 + ci] : 0.f;
        }
    }
    __syncthreads();

    float acc[4][8];
    #pragma unroll
    for (int j = 0; j < 4; ++j)
        #pragma unroll
        for (int i = 0; i < 8; ++i) acc[j][i] = 0.f;

    #pragma unroll 6
    for (int pos = 0; pos < 48; ++pos) {
        int r = pos/12, tc = pos - r*12;
        int t = tc/3,  ci = tc - t*3;
        float4 w0 = *(const float4*)&ws[pos*128 + c0];
        float4 w1 = *(const float4*)&ws[pos*128 + c0 + 4];
        #pragma unroll
        for (int j = 0; j < 4; ++j) {
            float av = xs[r][(2*(p0+j) + t)*3 + ci];
            acc[j][0] += av*w0.x; acc[j][1] += av*w0.y;
            acc[j][2] += av*w0.z; acc[j][3] += av*w0.w;
            acc[j][4] += av*w1.x; acc[j][5] += av*w1.y;
            acc[j][6] += av*w1.z; acc[j][7] += av*w1.w;
        }
    }
    float bv[8];
    #pragma unroll
    for (int i = 0; i < 8; ++i) bv[i] = bias[c0+i];
    #pragma unroll
    for (int j = 0; j < 4; ++j) {
        int ox = ox0 + p0 + j;
        float* o = out + (((size_t)(b*128) + oy)*128 + ox)*128 + c0;
        #pragma unroll
        for (int i = 0; i < 8; ++i) o[i] = gelu_f(acc[j][i] + bv[i]);
    }
}

// ---------------- conv2: h1 -> h2[16,64,64,128], 4x4 s2 SAME, GELU. pad=1.
// block: (b, oy), full 64-px output row. 256 thr: 16cg x 8ch, 16pg x 4px.
__global__ __launch_bounds__(256) void k_conv2(const float* __restrict__ in,
        const float* __restrict__ w, const float* __restrict__ bias,
        float* __restrict__ out) {
    __shared__ __align__(16) float xs[130*33];   // ixl 0..129, ci-slab 32 (pad 33)
    __shared__ __align__(16) float wb[32*128];
    const int tid = threadIdx.x;
    const int oy = blockIdx.x & 63;
    const int b  = blockIdx.x >> 6;
    const int cg = tid & 15, pg = tid >> 4;
    const int c0 = cg*8, p0 = pg*4;

    float acc[4][8];
    #pragma unroll
    for (int j = 0; j < 4; ++j)
        #pragma unroll
        for (int i = 0; i < 8; ++i) acc[j][i] = 0.f;

    for (int r = 0; r < 4; ++r) {
        int iy = 2*oy + r - 1;
        bool yok = (unsigned)iy < 128u;
        const float* inrow = in + ((size_t)(b*128) + iy)*128*128;
        for (int cs = 0; cs < 4; ++cs) {
            __syncthreads();
            for (int i = tid; i < 130*32; i += 256) {
                int ixl = i >> 5, ci = i & 31;
                int ix = ixl - 1;
                xs[ixl*33 + ci] = (yok && (unsigned)ix < 128u)
                    ? inrow[(size_t)ix*128 + cs*32 + ci] : 0.f;
            }
            for (int t = 0; t < 4; ++t) {
                __syncthreads();
                const float* wsrc = w + ((size_t)((r*4 + t)*128 + cs*32))*128;
                for (int i = tid; i < 4096; i += 256) wb[i] = wsrc[i];
                __syncthreads();
                #pragma unroll 8
                for (int ci = 0; ci < 32; ++ci) {
                    float a_[4];
                    #pragma unroll
                    for (int j = 0; j < 4; ++j) a_[j] = xs[(2*(p0+j) + t)*33 + ci];
                    float4 b0 = *(const float4*)&wb[ci*128 + c0];
                    float4 b1 = *(const float4*)&wb[ci*128 + c0 + 4];
                    #pragma unroll
                    for (int j = 0; j < 4; ++j) {
                        acc[j][0] += a_[j]*b0.x; acc[j][1] += a_[j]*b0.y;
                        acc[j][2] += a_[j]*b0.z; acc[j][3] += a_[j]*b0.w;
                        acc[j][4] += a_[j]*b1.x; acc[j][5] += a_[j]*b1.y;
                        acc[j][6] += a_[j]*b1.z; acc[j][7] += a_[j]*b1.w;
                    }
                }
            }
        }
    }
    float bv[8];
    #pragma unroll
    for (int i = 0; i < 8; ++i) bv[i] = bias[c0+i];
    #pragma unroll
    for (int j = 0; j < 4; ++j) {
        float* o = out + (((size_t)(b*64) + oy)*64 + (p0 + j))*128 + c0;
        #pragma unroll
        for (int i = 0; i < 8; ++i) o[i] = gelu_f(acc[j][i] + bv[i]);
    }
}

// ---------------- conv3 (1x1, 128->64, +bias, no act): h2 -> z_e [65536,64]
// block: 128 px. 256 thr: 8cg x 8ch, 32pg x 4px.
__global__ __launch_bounds__(256) void k_conv3(const float* __restrict__ in,
        const float* __restrict__ w, const float* __restrict__ bias,
        float* __restrict__ out) {
    __shared__ __align__(16) float xs[128*33];
    __shared__ __align__(16) float wb[32*64];
    const int tid = threadIdx.x;
    const size_t pix0 = (size_t)blockIdx.x * 128;
    const int cg = tid & 7, pg = tid >> 3;
    const int c0 = cg*8, p0 = pg*4;

    float acc[4][8];
    #pragma unroll
    for (int j = 0; j < 4; ++j)
        #pragma unroll
        for (int i = 0; i < 8; ++i) acc[j][i] = 0.f;

    for (int cs = 0; cs < 4; ++cs) {
        __syncthreads();
        for (int i = tid; i < 4096; i += 256) {
            int p = i >> 5, ci = i & 31;
            xs[p*33 + ci] = in[(pix0 + p)*128 + cs*32 + ci];
        }
        for (int i = tid; i < 2048; i += 256) {
            int ci = i >> 6, c = i & 63;
            wb[i] = w[(size_t)(cs*32 + ci)*64 + c];
        }
        __syncthreads();
        #pragma unroll 8
        for (int ci = 0; ci < 32; ++ci) {
            float a_[4];
            #pragma unroll
            for (int j = 0; j < 4; ++j) a_[j] = xs[(p0+j)*33 + ci];
            float4 b0 = *(const float4*)&wb[ci*64 + c0];
            float4 b1 = *(const float4*)&wb[ci*64 + c0 + 4];
            #pragma unroll
            for (int j = 0; j < 4; ++j) {
                acc[j][0] += a_[j]*b0.x; acc[j][1] += a_[j]*b0.y;
                acc[j][2] += a_[j]*b0.z; acc[j][3] += a_[j]*b0.w;
                acc[j][4] += a_[j]*b1.x; acc[j][5] += a_[j]*b1.y;
                acc[j][6] += a_[j]*b1.z; acc[j][7] += a_[j]*b1.w;
            }
        }
    }
    #pragma unroll
    for (int j = 0; j < 4; ++j) {
        float* o = out + (pix0 + p0 + j)*64 + c0;
        #pragma unroll
        for (int i = 0; i < 8; ++i) o[i] = acc[j][i] + bias[c0+i];
    }
}

// ---------------- VQ: z_e -> tok (float idx), z_q, sum((z_q-z_e)^2) atomic.
// dist = z2 + e2 - 2*dot (matches ref formula). First-min tie-break (lowest idx).
// block: 64 tokens. 256 thr: 16cg x 8codes, 4pg x 4toks (wait 16pg x 4toks).
__global__ __launch_bounds__(256) void k_vq(const float* __restrict__ ze,
        const float* __restrict__ cb, float* __restrict__ zq,
        float* __restrict__ tok, float* __restrict__ loss_acc) {
    __shared__ __align__(16) float zs[64*65];
    __shared__ __align__(16) float bt[64*132];   // transposed codebook chunk [d][k]
    __shared__ float es[128];
    __shared__ float z2s[64];
    __shared__ float rmin[64*16];
    __shared__ int   ridx[64*16];
    __shared__ int   widx[64];
    __shared__ float wsum[4];
    const int tid = threadIdx.x;
    const size_t tok0 = (size_t)blockIdx.x * 64;
    const int cg = tid & 15, pg = tid >> 4;
    const int k0 = cg*8, t0 = pg*4;

    for (int i = tid; i < 4096; i += 256) {
        int tk = i >> 6, d = i & 63;
        zs[tk*65 + d] = ze[(tok0 + tk)*64 + d];
    }
    __syncthreads();
    if (tid < 64) {
        float s = 0.f;
        for (int d = 0; d < 64; ++d) { float v = zs[tid*65 + d]; s += v*v; }
        z2s[tid] = s;
    }

    float bmin[4] = {3.4e38f,3.4e38f,3.4e38f,3.4e38f};
    int   bidx[4] = {0,0,0,0};

    for (int ch = 0; ch < 8; ++ch) {
        __syncthreads();
        for (int i = tid; i < 8192; i += 256) {
            int k = i >> 6, d = i & 63;
            bt[d*132 + k] = cb[((size_t)(ch*128) + k)*64 + d];
        }
        __syncthreads();
        if (tid < 128) {
            float s = 0.f;
            for (int d = 0; d < 64; ++d) { float v = bt[d*132 + tid]; s += v*v; }
            es[tid] = s;
        }
        __syncthreads();
        float acc[4][8];
        #pragma unroll
        for (int j = 0; j < 4; ++j)
            #pragma unroll
            for (int i = 0; i < 8; ++i) acc[j][i] = 0.f;
        #pragma unroll 4
        for (int d = 0; d < 64; ++d) {
            float a_[4];
            #pragma unroll
            for (int j = 0; j < 4; ++j) a_[j] = zs[(t0+j)*65 + d];
            float4 b0 = *(const float4*)&bt[d*132 + k0];
            float4 b1 = *(const float4*)&bt[d*132 + k0 + 4];
            #pragma unroll
            for (int j = 0; j < 4; ++j) {
                acc[j][0] += a_[j]*b0.x; acc[j][1] += a_[j]*b0.y;
                acc[j][2] += a_[j]*b0.z; acc[j][3] += a_[j]*b0.w;
                acc[j][4] += a_[j]*b1.x; acc[j][5] += a_[j]*b1.y;
                acc[j][6] += a_[j]*b1.z; acc[j][7] += a_[j]*b1.w;
            }
        }
        #pragma unroll
        for (int j = 0; j < 4; ++j) {
            float z2 = z2s[t0+j];
            #pragma unroll
            for (int i = 0; i < 8; ++i) {
                float dist = (z2 + es[k0+i]) - 2.f*acc[j][i];
                int idx = ch*128 + k0 + i;
                if (dist < bmin[j]) { bmin[j] = dist; bidx[j] = idx; }
            }
        }
    }
    #pragma unroll
    for (int j = 0; j < 4; ++j) {
        rmin[(t0+j)*16 + cg] = bmin[j];
        ridx[(t0+j)*16 + cg] = bidx[j];
    }
    __syncthreads();
    if (tid < 64) {
        float bv = rmin[tid*16]; int bi = ridx[tid*16];
        for (int g = 1; g < 16; ++g) {
            float v = rmin[tid*16 + g]; int ii = ridx[tid*16 + g];
            if (v < bv || (v == bv && ii < bi)) { bv = v; bi = ii; }
        }
        widx[tid] = bi;
        tok[tok0 + tid] = (float)bi;
    }
    __syncthreads();
    float lsum = 0.f;
    for (int i = tid; i < 4096; i += 256) {
        int tk = i >> 6, d = i & 63;
        float v = cb[(size_t)widx[tk]*64 + d];
        zq[(tok0 + tk)*64 + d] = v;
        float diff = v - zs[tk*65 + d];
        lsum += diff*diff;
    }
    #pragma unroll
    for (int off = 32; off > 0; off >>= 1) lsum += __shfl_down(lsum, off, 64);
    if ((tid & 63) == 0) wsum[tid >> 6] = lsum;
    __syncthreads();
    if (tid == 0) atomicAdd(loss_acc, wsum[0]+wsum[1]+wsum[2]+wsum[3]);
}

// ---------------- convT1: z_q[16,64,64,64] -> g1[16,128,128,128], 4x4 s2 SAME, GELU.
// jax conv_transpose pad_a=pad_b=2, no kernel flip: y[o] = sum_r dilated[o+r-2]*w[r].
// Parity decomposition: r in {ey, ey+2}, iy = q+ey-1+rr; t in {par, par+2}, ix = p+par-1+tt.
// block: (b, oy, par) -> 64 px. 256 thr: 16cg x 8ch, 16pg x 4px.
__global__ __launch_bounds__(256) void k_convt1(const float* __restrict__ zq,
        const float* __restrict__ w, const float* __restrict__ bias,
        float* __restrict__ out) {
    __shared__ __align__(16) float as_[64*65];
    __shared__ __align__(16) float wb[64*128];
    const int tid = threadIdx.x;
    const int par = blockIdx.x & 1;
    const int oy  = (blockIdx.x >> 1) & 127;
    const int b   = blockIdx.x >> 8;
    const int cg = tid & 15, pg = tid >> 4;
    const int c0 = cg*8, p0 = pg*4;
    const int ey = oy & 1, q = oy >> 1;

    float acc[4][8];
    #pragma unroll
    for (int j = 0; j < 4; ++j)
        #pragma unroll
        for (int i = 0; i < 8; ++i) acc[j][i] = 0.f;

    for (int tap = 0; tap < 4; ++tap) {
        int rr = tap >> 1, tt = tap & 1;
        int r = ey + rr*2, t = par + tt*2;
        int iy = q + ey - 1 + rr;
        bool yok = (unsigned)iy < 64u;
        const float* inrow = zq + ((size_t)(b*64) + iy)*64*64;
        __syncthreads();
        for (int i = tid; i < 4096; i += 256) {
            int p = i >> 6, ci = i & 63;
            int ix = p + par - 1 + tt;
            as_[p*65 + ci] = (yok && (unsigned)ix < 64u)
                ? inrow[(size_t)ix*64 + ci] : 0.f;
        }
        const float* wsrc = w + (size_t)((r*4 + t)*64)*128;
        for (int i = tid; i < 8192; i += 256) wb[i] = wsrc[i];
        __syncthreads();
        #pragma unroll 8
        for (int ci = 0; ci < 64; ++ci) {
            float a_[4];
            #pragma unroll
            for (int j = 0; j < 4; ++j) a_[j] = as_[(p0+j)*65 + ci];
            float4 b0 = *(const float4*)&wb[ci*128 + c0];
            float4 b1 = *(const float4*)&wb[ci*128 + c0 + 4];
            #pragma unroll
            for (int j = 0; j < 4; ++j) {
                acc[j][0] += a_[j]*b0.x; acc[j][1] += a_[j]*b0.y;
                acc[j][2] += a_[j]*b0.z; acc[j][3] += a_[j]*b0.w;
                acc[j][4] += a_[j]*b1.x; acc[j][5] += a_[j]*b1.y;
                acc[j][6] += a_[j]*b1.z; acc[j][7] += a_[j]*b1.w;
            }
        }
    }
    float bv[8];
    #pragma unroll
    for (int i = 0; i < 8; ++i) bv[i] = bias[c0+i];
    #pragma unroll
    for (int j = 0; j < 4; ++j) {
        int ox = par + 2*(p0 + j);
        float* o = out + (((size_t)(b*128) + oy)*128 + ox)*128 + c0;
        #pragma unroll
        for (int i = 0; i < 8; ++i) o[i] = gelu_f(acc[j][i] + bv[i]);
    }
}

// ---------------- convT2 + fused final 1x1: g1 -> x_rec[16,256,256,3]
// block: (b, oy, par) -> 128 px. 256 thr: 16cg x 8ch, 16pg x 8px (acc 8x8).
__global__ __launch_bounds__(256) void k_convt2(const float* __restrict__ g1,
        const float* __restrict__ w, const float* __restrict__ b2,
        const float* __restrict__ w3, const float* __restrict__ b3,
        float* __restrict__ xrec) {
    union SM {
        struct { float a[128*33]; float w[32*128]; } s;
        float red[128*48];
    };
    __shared__ __align__(16) SM sm;
    const int tid = threadIdx.x;
    const int par = blockIdx.x & 1;
    const int oy  = (blockIdx.x >> 1) & 255;
    const int b   = blockIdx.x >> 9;
    const int cg = tid & 15, pg = tid >> 4;
    const int c0 = cg*8, p0 = pg*8;
    const int ey = oy & 1, q = oy >> 1;

    float acc[8][8];
    #pragma unroll
    for (int j = 0; j < 8; ++j)
        #pragma unroll
        for (int i = 0; i < 8; ++i) acc[j][i] = 0.f;

    for (int tap = 0; tap < 4; ++tap) {
        int rr = tap >> 1, tt = tap & 1;
        int r = ey + rr*2, t = par + tt*2;
        int iy = q + ey - 1 + rr;
        bool yok = (unsigned)iy < 128u;
        const float* inrow = g1 + ((size_t)(b*128) + iy)*128*128;
        for (int cs = 0; cs < 4; ++cs) {
            __syncthreads();
            for (int i = tid; i < 4096; i += 256) {
                int p = i >> 5, ci = i & 31;
                int ix = p + par - 1 + tt;
                sm.s.a[p*33 + ci] = (yok && (unsigned)ix < 128u)
                    ? inrow[(size_t)ix*128 + cs*32 + ci] : 0.f;
            }
            const float* wsrc = w + (size_t)((r*4 + t)*128 + cs*32)*128;
            for (int i = tid; i < 4096; i += 256) sm.s.w[i] = wsrc[i];
            __syncthreads();
            #pragma unroll 4
            for (int ci = 0; ci < 32; ++ci) {
                float a_[8];
                #pragma unroll
                for (int j = 0; j < 8; ++j) a_[j] = sm.s.a[(p0+j)*33 + ci];
                float4 b0 = *(const float4*)&sm.s.w[ci*128 + c0];
                float4 b1 = *(const float4*)&sm.s.w[ci*128 + c0 + 4];
                #pragma unroll
                for (int j = 0; j < 8; ++j) {
                    acc[j][0] += a_[j]*b0.x; acc[j][1] += a_[j]*b0.y;
                    acc[j][2] += a_[j]*b0.z; acc[j][3] += a_[j]*b0.w;
                    acc[j][4] += a_[j]*b1.x; acc[j][5] += a_[j]*b1.y;
                    acc[j][6] += a_[j]*b1.z; acc[j][7] += a_[j]*b1.w;
                }
            }
        }
    }
    // epilogue: GELU + bias, project 128->3 (partial per cgroup), reduce in LDS
    float bv[8];
    #pragma unroll
    for (int i = 0; i < 8; ++i) bv[i] = b2[c0+i];
    float w3r[24];
    #pragma unroll
    for (int i = 0; i < 8; ++i) {
        w3r[i*3+0] = w3[(c0+i)*3 + 0];
        w3r[i*3+1] = w3[(c0+i)*3 + 1];
        w3r[i*3+2] = w3[(c0+i)*3 + 2];
    }
    __syncthreads();
    #pragma unroll
    for (int j = 0; j < 8; ++j) {
        float s0 = 0.f, s1 = 0.f, s2 = 0.f;
        #pragma unroll
        for (int i = 0; i < 8; ++i) {
            float y = gelu_f(acc[j][i] + bv[i]);
            s0 += y*w3r[i*3+0]; s1 += y*w3r[i*3+1]; s2 += y*w3r[i*3+2];
        }
        int px = p0 + j;
        sm.red[px*48 + cg*3 + 0] = s0;
        sm.red[px*48 + cg*3 + 1] = s1;
        sm.red[px*48 + cg*3 + 2] = s2;
    }
    __syncthreads();
    for (int o = tid; o < 384; o += 256) {
        int px = o/3, jj = o - px*3;
        float s = b3[jj];
        #pragma unroll
        for (int g = 0; g < 16; ++g) s += sm.red[px*48 + g*3 + jj];
        xrec[(((size_t)(b*256) + oy)*256 + (par + 2*px))*3 + jj] = s;
    }
}

__global__ void k_zero(float* p) { if (threadIdx.x == 0) p[0] = 0.f; }

__global__ void k_finalize(const float* __restrict__ loss_acc, float* __restrict__ o) {
    if (threadIdx.x == 0) {
        float v = loss_acc[0] * (1.0f/4194304.0f);  // mean over 65536*64
        o[0] = v;   // commit loss
        o[1] = v;   // codebook loss (same forward value)
    }
}

extern "C" void kernel_launch(void* const* d_in, const int* in_sizes, int n_in,
                              void* d_out, int out_size, void* d_ws, size_t ws_size,
                              hipStream_t stream) {
    (void)in_sizes; (void)n_in; (void)out_size; (void)ws_size;
    const float* x   = (const float*)d_in[0];
    const float* ew1 = (const float*)d_in[1];
    const float* eb1 = (const float*)d_in[2];
    const float* ew2 = (const float*)d_in[3];
    const float* eb2 = (const float*)d_in[4];
    const float* ew3 = (const float*)d_in[5];
    const float* eb3 = (const float*)d_in[6];
    const float* cb  = (const float*)d_in[7];
    const float* dw1 = (const float*)d_in[8];
    const float* db1 = (const float*)d_in[9];
    const float* dw2 = (const float*)d_in[10];
    const float* db2 = (const float*)d_in[11];
    const float* dw3 = (const float*)d_in[12];
    const float* db3 = (const float*)d_in[13];

    float* ws   = (float*)d_ws;
    float* h1   = ws;                       // 33,554,432 f  (reused as g1)
    float* h2   = h1 + 33554432;            //  8,388,608 f
    float* ze   = h2 + 8388608;             //  4,194,304 f
    float* zq   = ze + 4194304;             //  4,194,304 f
    float* lacc = zq + 4194304;             //          1 f

    float* xrec = (float*)d_out;            // 3,145,728 f
    float* tokf = xrec + 3145728;           //    65,536 f
    float* loss = tokf + 65536;             //         2 f

    k_conv1   <<<4096, 256, 0, stream>>>(x, ew1, eb1, h1);
    k_conv2   <<<1024, 256, 0, stream>>>(h1, ew2, eb2, h2);
    k_conv3   <<< 512, 256, 0, stream>>>(h2, ew3, eb3, ze);
    k_zero    <<<   1,  64, 0, stream>>>(lacc);
    k_vq      <<<1024, 256, 0, stream>>>(ze, cb, zq, tokf, lacc);
    k_convt1  <<<4096, 256, 0, stream>>>(zq, dw1, db1, h1);     // g1 reuses h1
    k_convt2  <<<8192, 256, 0, stream>>>(h1, dw2, db2, dw3, db3, xrec);
    k_finalize<<<   1,  64, 0, stream>>>(lacc, loss);
}

// Round 2
// 2843.387 us; speedup vs baseline: 1.0449x; 1.0449x over previous
//
#include <hip/hip_runtime.h>
#include <math.h>

// Shapes: B=16, x[16,256,256,3], h1[16,128,128,128], h2[16,64,64,128],
// z_e/z_q[65536,64], g1[16,128,128,128], x_rec[16,256,256,3], K=1024 codes.
//
// R2: LDS bank-conflict fix. All weight/codebook float4 reads were
// cg*8-strided (32B lane stride -> 4-way bank aliasing, 1.58x). Split each
// lane's 8 channels into two float4 groups at cg*4 and HALF+cg*4 (16B lane
// stride -> 256B contiguous per wave -> 2-way aliasing = free, m136).

__device__ __forceinline__ float gelu_f(float x) {
    float x3 = x*x*x;
    return 0.5f*x*(1.0f + tanhf(0.7978845608028654f*(x + 0.044715f*x3)));
}

// ---------------- conv1: x[16,256,256,3] -> h1[16,128,128,128], 4x4 s2 SAME, GELU
__global__ __launch_bounds__(256) void k_conv1(const float* __restrict__ x,
        const float* __restrict__ w, const float* __restrict__ bias,
        float* __restrict__ out) {
    __shared__ __align__(16) float ws[48*128];
    __shared__ __align__(16) float xs[4][390];   // 130 ix-positions x 3 ci
    const int tid = threadIdx.x;
    const int blk = blockIdx.x;
    const int oxt = blk & 1;
    const int oy  = (blk >> 1) & 127;
    const int b   = blk >> 8;
    const int cg = tid & 15, pg = tid >> 4;
    const int c0a = cg*4, c0b = 64 + cg*4;
    const int p0 = pg*4;
    const int ox0 = oxt*64;

    for (int i = tid; i < 6144; i += 256) ws[i] = w[i];
    for (int r = 0; r < 4; ++r) {
        int iy = 2*oy + r - 1;
        bool yok = (unsigned)iy < 256u;
        const float* xrow = x + ((size_t)(b*256) + iy)*256*3;
        for (int i = tid; i < 390; i += 256) {
            int ixl = i/3, ci = i - ixl*3;
            int ix = 2*ox0 - 1 + ixl;
            xs[r][i] = (yok && (unsigned)ix < 256u) ? xrow[(size_t)ix*3 + ci] : 0.f;
        }
    }
    __syncthreads();

    float acc[4][8];
    #pragma unroll
    for (int j = 0; j < 4; ++j)
        #pragma unroll
        for (int i = 0; i < 8; ++i) acc[j][i] = 0.f;

    #pragma unroll 6
    for (int pos = 0; pos < 48; ++pos) {
        int r = pos/12, tc = pos - r*12;
        int t = tc/3,  ci = tc - t*3;
        float4 w0 = *(const float4*)&ws[pos*128 + c0a];
        float4 w1 = *(const float4*)&ws[pos*128 + c0b];
        #pragma unroll
        for (int j = 0; j < 4; ++j) {
            float av = xs[r][(2*(p0+j) + t)*3 + ci];
            acc[j][0] += av*w0.x; acc[j][1] += av*w0.y;
            acc[j][2] += av*w0.z; acc[j][3] += av*w0.w;
            acc[j][4] += av*w1.x; acc[j][5] += av*w1.y;
            acc[j][6] += av*w1.z; acc[j][7] += av*w1.w;
        }
    }
    float bv[8];
    #pragma unroll
    for (int i = 0; i < 4; ++i) { bv[i] = bias[c0a+i]; bv[4+i] = bias[c0b+i]; }
    #pragma unroll
    for (int j = 0; j < 4; ++j) {
        int ox = ox0 + p0 + j;
        float* o = out + (((size_t)(b*128) + oy)*128 + ox)*128;
        float4 va, vb;
        va.x = gelu_f(acc[j][0]+bv[0]); va.y = gelu_f(acc[j][1]+bv[1]);
        va.z = gelu_f(acc[j][2]+bv[2]); va.w = gelu_f(acc[j][3]+bv[3]);
        vb.x = gelu_f(acc[j][4]+bv[4]); vb.y = gelu_f(acc[j][5]+bv[5]);
        vb.z = gelu_f(acc[j][6]+bv[6]); vb.w = gelu_f(acc[j][7]+bv[7]);
        *(float4*)&o[c0a] = va;
        *(float4*)&o[c0b] = vb;
    }
}

// ---------------- conv2: h1 -> h2[16,64,64,128], 4x4 s2 SAME, GELU. pad=1.
__global__ __launch_bounds__(256) void k_conv2(const float* __restrict__ in,
        const float* __restrict__ w, const float* __restrict__ bias,
        float* __restrict__ out) {
    __shared__ __align__(16) float xs[130*33];   // ixl 0..129, ci-slab 32 (pad 33)
    __shared__ __align__(16) float wb[32*128];
    const int tid = threadIdx.x;
    const int oy = blockIdx.x & 63;
    const int b  = blockIdx.x >> 6;
    const int cg = tid & 15, pg = tid >> 4;
    const int c0a = cg*4, c0b = 64 + cg*4;
    const int p0 = pg*4;

    float acc[4][8];
    #pragma unroll
    for (int j = 0; j < 4; ++j)
        #pragma unroll
        for (int i = 0; i < 8; ++i) acc[j][i] = 0.f;

    for (int r = 0; r < 4; ++r) {
        int iy = 2*oy + r - 1;
        bool yok = (unsigned)iy < 128u;
        const float* inrow = in + ((size_t)(b*128) + iy)*128*128;
        for (int cs = 0; cs < 4; ++cs) {
            __syncthreads();
            for (int i = tid; i < 130*32; i += 256) {
                int ixl = i >> 5, ci = i & 31;
                int ix = ixl - 1;
                xs[ixl*33 + ci] = (yok && (unsigned)ix < 128u)
                    ? inrow[(size_t)ix*128 + cs*32 + ci] : 0.f;
            }
            for (int t = 0; t < 4; ++t) {
                __syncthreads();
                const float* wsrc = w + ((size_t)((r*4 + t)*128 + cs*32))*128;
                for (int i = tid; i < 4096; i += 256) wb[i] = wsrc[i];
                __syncthreads();
                #pragma unroll 8
                for (int ci = 0; ci < 32; ++ci) {
                    float a_[4];
                    #pragma unroll
                    for (int j = 0; j < 4; ++j) a_[j] = xs[(2*(p0+j) + t)*33 + ci];
                    float4 b0 = *(const float4*)&wb[ci*128 + c0a];
                    float4 b1 = *(const float4*)&wb[ci*128 + c0b];
                    #pragma unroll
                    for (int j = 0; j < 4; ++j) {
                        acc[j][0] += a_[j]*b0.x; acc[j][1] += a_[j]*b0.y;
                        acc[j][2] += a_[j]*b0.z; acc[j][3] += a_[j]*b0.w;
                        acc[j][4] += a_[j]*b1.x; acc[j][5] += a_[j]*b1.y;
                        acc[j][6] += a_[j]*b1.z; acc[j][7] += a_[j]*b1.w;
                    }
                }
            }
        }
    }
    float bv[8];
    #pragma unroll
    for (int i = 0; i < 4; ++i) { bv[i] = bias[c0a+i]; bv[4+i] = bias[c0b+i]; }
    #pragma unroll
    for (int j = 0; j < 4; ++j) {
        float* o = out + (((size_t)(b*64) + oy)*64 + (p0 + j))*128;
        float4 va, vb;
        va.x = gelu_f(acc[j][0]+bv[0]); va.y = gelu_f(acc[j][1]+bv[1]);
        va.z = gelu_f(acc[j][2]+bv[2]); va.w = gelu_f(acc[j][3]+bv[3]);
        vb.x = gelu_f(acc[j][4]+bv[4]); vb.y = gelu_f(acc[j][5]+bv[5]);
        vb.z = gelu_f(acc[j][6]+bv[6]); vb.w = gelu_f(acc[j][7]+bv[7]);
        *(float4*)&o[c0a] = va;
        *(float4*)&o[c0b] = vb;
    }
}

// ---------------- conv3 (1x1, 128->64, +bias, no act): h2 -> z_e [65536,64]
__global__ __launch_bounds__(256) void k_conv3(const float* __restrict__ in,
        const float* __restrict__ w, const float* __restrict__ bias,
        float* __restrict__ out) {
    __shared__ __align__(16) float xs[128*33];
    __shared__ __align__(16) float wb[32*64];
    const int tid = threadIdx.x;
    const size_t pix0 = (size_t)blockIdx.x * 128;
    const int cg = tid & 7, pg = tid >> 3;
    const int c0a = cg*4, c0b = 32 + cg*4;
    const int p0 = pg*4;

    float acc[4][8];
    #pragma unroll
    for (int j = 0; j < 4; ++j)
        #pragma unroll
        for (int i = 0; i < 8; ++i) acc[j][i] = 0.f;

    for (int cs = 0; cs < 4; ++cs) {
        __syncthreads();
        for (int i = tid; i < 4096; i += 256) {
            int p = i >> 5, ci = i & 31;
            xs[p*33 + ci] = in[(pix0 + p)*128 + cs*32 + ci];
        }
        for (int i = tid; i < 2048; i += 256) {
            int ci = i >> 6, c = i & 63;
            wb[i] = w[(size_t)(cs*32 + ci)*64 + c];
        }
        __syncthreads();
        #pragma unroll 8
        for (int ci = 0; ci < 32; ++ci) {
            float a_[4];
            #pragma unroll
            for (int j = 0; j < 4; ++j) a_[j] = xs[(p0+j)*33 + ci];
            float4 b0 = *(const float4*)&wb[ci*64 + c0a];
            float4 b1 = *(const float4*)&wb[ci*64 + c0b];
            #pragma unroll
            for (int j = 0; j < 4; ++j) {
                acc[j][0] += a_[j]*b0.x; acc[j][1] += a_[j]*b0.y;
                acc[j][2] += a_[j]*b0.z; acc[j][3] += a_[j]*b0.w;
                acc[j][4] += a_[j]*b1.x; acc[j][5] += a_[j]*b1.y;
                acc[j][6] += a_[j]*b1.z; acc[j][7] += a_[j]*b1.w;
            }
        }
    }
    #pragma unroll
    for (int j = 0; j < 4; ++j) {
        float* o = out + (pix0 + p0 + j)*64;
        float4 va, vb;
        va.x = acc[j][0]+bias[c0a+0]; va.y = acc[j][1]+bias[c0a+1];
        va.z = acc[j][2]+bias[c0a+2]; va.w = acc[j][3]+bias[c0a+3];
        vb.x = acc[j][4]+bias[c0b+0]; vb.y = acc[j][5]+bias[c0b+1];
        vb.z = acc[j][6]+bias[c0b+2]; vb.w = acc[j][7]+bias[c0b+3];
        *(float4*)&o[c0a] = va;
        *(float4*)&o[c0b] = vb;
    }
}

// ---------------- VQ: z_e -> tok (float idx), z_q, sum((z_q-z_e)^2) atomic.
// dist = z2 + e2 - 2*dot (matches ref formula). First-min tie-break (lowest idx).
__global__ __launch_bounds__(256) void k_vq(const float* __restrict__ ze,
        const float* __restrict__ cb, float* __restrict__ zq,
        float* __restrict__ tok, float* __restrict__ loss_acc) {
    __shared__ __align__(16) float zs[64*65];
    __shared__ __align__(16) float bt[64*132];   // transposed codebook chunk [d][k]
    __shared__ float es[128];
    __shared__ float z2s[64];
    __shared__ float rmin[64*16];
    __shared__ int   ridx[64*16];
    __shared__ int   widx[64];
    __shared__ float wsum[4];
    const int tid = threadIdx.x;
    const size_t tok0 = (size_t)blockIdx.x * 64;
    const int cg = tid & 15, pg = tid >> 4;
    const int k0a = cg*4, k0b = 64 + cg*4;
    const int t0 = pg*4;

    for (int i = tid; i < 4096; i += 256) {
        int tk = i >> 6, d = i & 63;
        zs[tk*65 + d] = ze[(tok0 + tk)*64 + d];
    }
    __syncthreads();
    if (tid < 64) {
        float s = 0.f;
        for (int d = 0; d < 64; ++d) { float v = zs[tid*65 + d]; s += v*v; }
        z2s[tid] = s;
    }

    float bmin[4] = {3.4e38f,3.4e38f,3.4e38f,3.4e38f};
    int   bidx[4] = {0,0,0,0};

    for (int ch = 0; ch < 8; ++ch) {
        __syncthreads();
        for (int i = tid; i < 8192; i += 256) {
            int k = i >> 6, d = i & 63;
            bt[d*132 + k] = cb[((size_t)(ch*128) + k)*64 + d];
        }
        __syncthreads();
        if (tid < 128) {
            float s = 0.f;
            for (int d = 0; d < 64; ++d) { float v = bt[d*132 + tid]; s += v*v; }
            es[tid] = s;
        }
        __syncthreads();
        float acc[4][8];
        #pragma unroll
        for (int j = 0; j < 4; ++j)
            #pragma unroll
            for (int i = 0; i < 8; ++i) acc[j][i] = 0.f;
        #pragma unroll 4
        for (int d = 0; d < 64; ++d) {
            float a_[4];
            #pragma unroll
            for (int j = 0; j < 4; ++j) a_[j] = zs[(t0+j)*65 + d];
            float4 b0 = *(const float4*)&bt[d*132 + k0a];
            float4 b1 = *(const float4*)&bt[d*132 + k0b];
            #pragma unroll
            for (int j = 0; j < 4; ++j) {
                acc[j][0] += a_[j]*b0.x; acc[j][1] += a_[j]*b0.y;
                acc[j][2] += a_[j]*b0.z; acc[j][3] += a_[j]*b0.w;
                acc[j][4] += a_[j]*b1.x; acc[j][5] += a_[j]*b1.y;
                acc[j][6] += a_[j]*b1.z; acc[j][7] += a_[j]*b1.w;
            }
        }
        #pragma unroll
        for (int j = 0; j < 4; ++j) {
            float z2 = z2s[t0+j];
            #pragma unroll
            for (int i = 0; i < 4; ++i) {
                float dist = (z2 + es[k0a+i]) - 2.f*acc[j][i];
                int idx = ch*128 + k0a + i;
                if (dist < bmin[j]) { bmin[j] = dist; bidx[j] = idx; }
            }
            #pragma unroll
            for (int i = 0; i < 4; ++i) {
                float dist = (z2 + es[k0b+i]) - 2.f*acc[j][4+i];
                int idx = ch*128 + k0b + i;
                if (dist < bmin[j]) { bmin[j] = dist; bidx[j] = idx; }
            }
        }
    }
    #pragma unroll
    for (int j = 0; j < 4; ++j) {
        rmin[(t0+j)*16 + cg] = bmin[j];
        ridx[(t0+j)*16 + cg] = bidx[j];
    }
    __syncthreads();
    if (tid < 64) {
        float bv = rmin[tid*16]; int bi = ridx[tid*16];
        for (int g = 1; g < 16; ++g) {
            float v = rmin[tid*16 + g]; int ii = ridx[tid*16 + g];
            if (v < bv || (v == bv && ii < bi)) { bv = v; bi = ii; }
        }
        widx[tid] = bi;
        tok[tok0 + tid] = (float)bi;
    }
    __syncthreads();
    float lsum = 0.f;
    for (int i = tid; i < 4096; i += 256) {
        int tk = i >> 6, d = i & 63;
        float v = cb[(size_t)widx[tk]*64 + d];
        zq[(tok0 + tk)*64 + d] = v;
        float diff = v - zs[tk*65 + d];
        lsum += diff*diff;
    }
    #pragma unroll
    for (int off = 32; off > 0; off >>= 1) lsum += __shfl_down(lsum, off, 64);
    if ((tid & 63) == 0) wsum[tid >> 6] = lsum;
    __syncthreads();
    if (tid == 0) atomicAdd(loss_acc, wsum[0]+wsum[1]+wsum[2]+wsum[3]);
}

// ---------------- convT1: z_q[16,64,64,64] -> g1[16,128,128,128], 4x4 s2 SAME, GELU.
__global__ __launch_bounds__(256) void k_convt1(const float* __restrict__ zq,
        const float* __restrict__ w, const float* __restrict__ bias,
        float* __restrict__ out) {
    __shared__ __align__(16) float as_[64*65];
    __shared__ __align__(16) float wb[64*128];
    const int tid = threadIdx.x;
    const int par = blockIdx.x & 1;
    const int oy  = (blockIdx.x >> 1) & 127;
    const int b   = blockIdx.x >> 8;
    const int cg = tid & 15, pg = tid >> 4;
    const int c0a = cg*4, c0b = 64 + cg*4;
    const int p0 = pg*4;
    const int ey = oy & 1, q = oy >> 1;

    float acc[4][8];
    #pragma unroll
    for (int j = 0; j < 4; ++j)
        #pragma unroll
        for (int i = 0; i < 8; ++i) acc[j][i] = 0.f;

    for (int tap = 0; tap < 4; ++tap) {
        int rr = tap >> 1, tt = tap & 1;
        int r = ey + rr*2, t = par + tt*2;
        int iy = q + ey - 1 + rr;
        bool yok = (unsigned)iy < 64u;
        const float* inrow = zq + ((size_t)(b*64) + iy)*64*64;
        __syncthreads();
        for (int i = tid; i < 4096; i += 256) {
            int p = i >> 6, ci = i & 63;
            int ix = p + par - 1 + tt;
            as_[p*65 + ci] = (yok && (unsigned)ix < 64u)
                ? inrow[(size_t)ix*64 + ci] : 0.f;
        }
        const float* wsrc = w + (size_t)((r*4 + t)*64)*128;
        for (int i = tid; i < 8192; i += 256) wb[i] = wsrc[i];
        __syncthreads();
        #pragma unroll 8
        for (int ci = 0; ci < 64; ++ci) {
            float a_[4];
            #pragma unroll
            for (int j = 0; j < 4; ++j) a_[j] = as_[(p0+j)*65 + ci];
            float4 b0 = *(const float4*)&wb[ci*128 + c0a];
            float4 b1 = *(const float4*)&wb[ci*128 + c0b];
            #pragma unroll
            for (int j = 0; j < 4; ++j) {
                acc[j][0] += a_[j]*b0.x; acc[j][1] += a_[j]*b0.y;
                acc[j][2] += a_[j]*b0.z; acc[j][3] += a_[j]*b0.w;
                acc[j][4] += a_[j]*b1.x; acc[j][5] += a_[j]*b1.y;
                acc[j][6] += a_[j]*b1.z; acc[j][7] += a_[j]*b1.w;
            }
        }
    }
    float bv[8];
    #pragma unroll
    for (int i = 0; i < 4; ++i) { bv[i] = bias[c0a+i]; bv[4+i] = bias[c0b+i]; }
    #pragma unroll
    for (int j = 0; j < 4; ++j) {
        int ox = par + 2*(p0 + j);
        float* o = out + (((size_t)(b*128) + oy)*128 + ox)*128;
        float4 va, vb;
        va.x = gelu_f(acc[j][0]+bv[0]); va.y = gelu_f(acc[j][1]+bv[1]);
        va.z = gelu_f(acc[j][2]+bv[2]); va.w = gelu_f(acc[j][3]+bv[3]);
        vb.x = gelu_f(acc[j][4]+bv[4]); vb.y = gelu_f(acc[j][5]+bv[5]);
        vb.z = gelu_f(acc[j][6]+bv[6]); vb.w = gelu_f(acc[j][7]+bv[7]);
        *(float4*)&o[c0a] = va;
        *(float4*)&o[c0b] = vb;
    }
}

// ---------------- convT2 + fused final 1x1: g1 -> x_rec[16,256,256,3]
__global__ __launch_bounds__(256) void k_convt2(const float* __restrict__ g1,
        const float* __restrict__ w, const float* __restrict__ b2,
        const float* __restrict__ w3, const float* __restrict__ b3,
        float* __restrict__ xrec) {
    union SM {
        struct { float a[128*33]; float w[32*128]; } s;
        float red[128*48];
    };
    __shared__ __align__(16) SM sm;
    const int tid = threadIdx.x;
    const int par = blockIdx.x & 1;
    const int oy  = (blockIdx.x >> 1) & 255;
    const int b   = blockIdx.x >> 9;
    const int cg = tid & 15, pg = tid >> 4;
    const int c0a = cg*4, c0b = 64 + cg*4;
    const int p0 = pg*8;
    const int ey = oy & 1, q = oy >> 1;

    float acc[8][8];
    #pragma unroll
    for (int j = 0; j < 8; ++j)
        #pragma unroll
        for (int i = 0; i < 8; ++i) acc[j][i] = 0.f;

    for (int tap = 0; tap < 4; ++tap) {
        int rr = tap >> 1, tt = tap & 1;
        int r = ey + rr*2, t = par + tt*2;
        int iy = q + ey - 1 + rr;
        bool yok = (unsigned)iy < 128u;
        const float* inrow = g1 + ((size_t)(b*128) + iy)*128*128;
        for (int cs = 0; cs < 4; ++cs) {
            __syncthreads();
            for (int i = tid; i < 4096; i += 256) {
                int p = i >> 5, ci = i & 31;
                int ix = p + par - 1 + tt;
                sm.s.a[p*33 + ci] = (yok && (unsigned)ix < 128u)
                    ? inrow[(size_t)ix*128 + cs*32 + ci] : 0.f;
            }
            const float* wsrc = w + (size_t)((r*4 + t)*128 + cs*32)*128;
            for (int i = tid; i < 4096; i += 256) sm.s.w[i] = wsrc[i];
            __syncthreads();
            #pragma unroll 4
            for (int ci = 0; ci < 32; ++ci) {
                float a_[8];
                #pragma unroll
                for (int j = 0; j < 8; ++j) a_[j] = sm.s.a[(p0+j)*33 + ci];
                float4 b0 = *(const float4*)&sm.s.w[ci*128 + c0a];
                float4 b1 = *(const float4*)&sm.s.w[ci*128 + c0b];
                #pragma unroll
                for (int j = 0; j < 8; ++j) {
                    acc[j][0] += a_[j]*b0.x; acc[j][1] += a_[j]*b0.y;
                    acc[j][2] += a_[j]*b0.z; acc[j][3] += a_[j]*b0.w;
                    acc[j][4] += a_[j]*b1.x; acc[j][5] += a_[j]*b1.y;
                    acc[j][6] += a_[j]*b1.z; acc[j][7] += a_[j]*b1.w;
                }
            }
        }
    }
    // epilogue: GELU + bias, project 128->3 (partial per cgroup), reduce in LDS
    float bv[8];
    #pragma unroll
    for (int i = 0; i < 4; ++i) { bv[i] = b2[c0a+i]; bv[4+i] = b2[c0b+i]; }
    float w3r[24];
    #pragma unroll
    for (int i = 0; i < 4; ++i) {
        w3r[i*3+0] = w3[(c0a+i)*3 + 0];
        w3r[i*3+1] = w3[(c0a+i)*3 + 1];
        w3r[i*3+2] = w3[(c0a+i)*3 + 2];
        w3r[(4+i)*3+0] = w3[(c0b+i)*3 + 0];
        w3r[(4+i)*3+1] = w3[(c0b+i)*3 + 1];
        w3r[(4+i)*3+2] = w3[(c0b+i)*3 + 2];
    }
    __syncthreads();
    #pragma unroll
    for (int j = 0; j < 8; ++j) {
        float s0 = 0.f, s1 = 0.f, s2 = 0.f;
        #pragma unroll
        for (int i = 0; i < 8; ++i) {
            float y = gelu_f(acc[j][i] + bv[i]);
            s0 += y*w3r[i*3+0]; s1 += y*w3r[i*3+1]; s2 += y*w3r[i*3+2];
        }
        int px = p0 + j;
        sm.red[px*48 + cg*3 + 0] = s0;
        sm.red[px*48 + cg*3 + 1] = s1;
        sm.red[px*48 + cg*3 + 2] = s2;
    }
    __syncthreads();
    for (int o = tid; o < 384; o += 256) {
        int px = o/3, jj = o - px*3;
        float s = b3[jj];
        #pragma unroll
        for (int g = 0; g < 16; ++g) s += sm.red[px*48 + g*3 + jj];
        xrec[(((size_t)(b*256) + oy)*256 + (par + 2*px))*3 + jj] = s;
    }
}

__global__ void k_zero(float* p) { if (threadIdx.x == 0) p[0] = 0.f; }

__global__ void k_finalize(const float* __restrict__ loss_acc, float* __restrict__ o) {
    if (threadIdx.x == 0) {
        float v = loss_acc[0] * (1.0f/4194304.0f);  // mean over 65536*64
        o[0] = v;   // commit loss
        o[1] = v;   // codebook loss (same forward value)
    }
}

extern "C" void kernel_launch(void* const* d_in, const int* in_sizes, int n_in,
                              void* d_out, int out_size, void* d_ws, size_t ws_size,
                              hipStream_t stream) {
    (void)in_sizes; (void)n_in; (void)out_size; (void)ws_size;
    const float* x   = (const float*)d_in[0];
    const float* ew1 = (const float*)d_in[1];
    const float* eb1 = (const float*)d_in[2];
    const float* ew2 = (const float*)d_in[3];
    const float* eb2 = (const float*)d_in[4];
    const float* ew3 = (const float*)d_in[5];
    const float* eb3 = (const float*)d_in[6];
    const float* cb  = (const float*)d_in[7];
    const float* dw1 = (const float*)d_in[8];
    const float* db1 = (const float*)d_in[9];
    const float* dw2 = (const float*)d_in[10];
    const float* db2 = (const float*)d_in[11];
    const float* dw3 = (const float*)d_in[12];
    const float* db3 = (const float*)d_in[13];

    float* ws   = (float*)d_ws;
    float* h1   = ws;                       // 33,554,432 f  (reused as g1)
    float* h2   = h1 + 33554432;            //  8,388,608 f
    float* ze   = h2 + 8388608;             //  4,194,304 f
    float* zq   = ze + 4194304;             //  4,194,304 f
    float* lacc = zq + 4194304;             //          1 f

    float* xrec = (float*)d_out;            // 3,145,728 f
    float* tokf = xrec + 3145728;           //    65,536 f
    float* loss = tokf + 65536;             //         2 f

    k_conv1   <<<4096, 256, 0, stream>>>(x, ew1, eb1, h1);
    k_conv2   <<<1024, 256, 0, stream>>>(h1, ew2, eb2, h2);
    k_conv3   <<< 512, 256, 0, stream>>>(h2, ew3, eb3, ze);
    k_zero    <<<   1,  64, 0, stream>>>(lacc);
    k_vq      <<<1024, 256, 0, stream>>>(ze, cb, zq, tokf, lacc);
    k_convt1  <<<4096, 256, 0, stream>>>(zq, dw1, db1, h1);     // g1 reuses h1
    k_convt2  <<<8192, 256, 0, stream>>>(h1, dw2, db2, dw3, db3, xrec);
    k_finalize<<<   1,  64, 0, stream>>>(lacc, loss);
}

// Round 3
// 1505.439 us; speedup vs baseline: 1.9735x; 1.8887x over previous
//
#include <hip/hip_runtime.h>
#include <math.h>

// Shapes: B=16, x[16,256,256,3], h1[16,128,128,128], h2[16,64,64,128],
// z_e/z_q[65536,64], g1[16,128,128,128](bf16), x_rec[16,256,256,3], K=1024.
//
// R3: convt2 -> bf16 MFMA implicit GEMM (M=128px, N=128co, K=512).
// convt1 now writes g1 in bf16 (RNE); dw2 pre-converted to bf16 [rt][co][ci].
// Encoder + VQ unchanged (tok/losses bit-identical to R2).

typedef __attribute__((ext_vector_type(8))) short short8;
typedef __attribute__((ext_vector_type(4))) float f32x4;

__device__ __forceinline__ float gelu_f(float x) {
    float x3 = x*x*x;
    return 0.5f*x*(1.0f + tanhf(0.7978845608028654f*(x + 0.044715f*x3)));
}

__device__ __forceinline__ unsigned short f2bf(float f) {
    unsigned int u = __float_as_uint(f);
    u = (u + 0x7FFFu + ((u >> 16) & 1u)) >> 16;   // RNE
    return (unsigned short)u;
}

// ---------------- conv1: x[16,256,256,3] -> h1[16,128,128,128], 4x4 s2 SAME, GELU
__global__ __launch_bounds__(256) void k_conv1(const float* __restrict__ x,
        const float* __restrict__ w, const float* __restrict__ bias,
        float* __restrict__ out) {
    __shared__ __align__(16) float ws[48*128];
    __shared__ __align__(16) float xs[4][390];
    const int tid = threadIdx.x;
    const int blk = blockIdx.x;
    const int oxt = blk & 1;
    const int oy  = (blk >> 1) & 127;
    const int b   = blk >> 8;
    const int cg = tid & 15, pg = tid >> 4;
    const int c0a = cg*4, c0b = 64 + cg*4;
    const int p0 = pg*4;
    const int ox0 = oxt*64;

    for (int i = tid; i < 6144; i += 256) ws[i] = w[i];
    for (int r = 0; r < 4; ++r) {
        int iy = 2*oy + r - 1;
        bool yok = (unsigned)iy < 256u;
        const float* xrow = x + ((size_t)(b*256) + iy)*256*3;
        for (int i = tid; i < 390; i += 256) {
            int ixl = i/3, ci = i - ixl*3;
            int ix = 2*ox0 - 1 + ixl;
            xs[r][i] = (yok && (unsigned)ix < 256u) ? xrow[(size_t)ix*3 + ci] : 0.f;
        }
    }
    __syncthreads();

    float acc[4][8];
    #pragma unroll
    for (int j = 0; j < 4; ++j)
        #pragma unroll
        for (int i = 0; i < 8; ++i) acc[j][i] = 0.f;

    #pragma unroll 6
    for (int pos = 0; pos < 48; ++pos) {
        int r = pos/12, tc = pos - r*12;
        int t = tc/3,  ci = tc - t*3;
        float4 w0 = *(const float4*)&ws[pos*128 + c0a];
        float4 w1 = *(const float4*)&ws[pos*128 + c0b];
        #pragma unroll
        for (int j = 0; j < 4; ++j) {
            float av = xs[r][(2*(p0+j) + t)*3 + ci];
            acc[j][0] += av*w0.x; acc[j][1] += av*w0.y;
            acc[j][2] += av*w0.z; acc[j][3] += av*w0.w;
            acc[j][4] += av*w1.x; acc[j][5] += av*w1.y;
            acc[j][6] += av*w1.z; acc[j][7] += av*w1.w;
        }
    }
    float bv[8];
    #pragma unroll
    for (int i = 0; i < 4; ++i) { bv[i] = bias[c0a+i]; bv[4+i] = bias[c0b+i]; }
    #pragma unroll
    for (int j = 0; j < 4; ++j) {
        int ox = ox0 + p0 + j;
        float* o = out + (((size_t)(b*128) + oy)*128 + ox)*128;
        float4 va, vb;
        va.x = gelu_f(acc[j][0]+bv[0]); va.y = gelu_f(acc[j][1]+bv[1]);
        va.z = gelu_f(acc[j][2]+bv[2]); va.w = gelu_f(acc[j][3]+bv[3]);
        vb.x = gelu_f(acc[j][4]+bv[4]); vb.y = gelu_f(acc[j][5]+bv[5]);
        vb.z = gelu_f(acc[j][6]+bv[6]); vb.w = gelu_f(acc[j][7]+bv[7]);
        *(float4*)&o[c0a] = va;
        *(float4*)&o[c0b] = vb;
    }
}

// ---------------- conv2: h1 -> h2[16,64,64,128], 4x4 s2 SAME, GELU. pad=1.
__global__ __launch_bounds__(256) void k_conv2(const float* __restrict__ in,
        const float* __restrict__ w, const float* __restrict__ bias,
        float* __restrict__ out) {
    __shared__ __align__(16) float xs[130*33];
    __shared__ __align__(16) float wb[32*128];
    const int tid = threadIdx.x;
    const int oy = blockIdx.x & 63;
    const int b  = blockIdx.x >> 6;
    const int cg = tid & 15, pg = tid >> 4;
    const int c0a = cg*4, c0b = 64 + cg*4;
    const int p0 = pg*4;

    float acc[4][8];
    #pragma unroll
    for (int j = 0; j < 4; ++j)
        #pragma unroll
        for (int i = 0; i < 8; ++i) acc[j][i] = 0.f;

    for (int r = 0; r < 4; ++r) {
        int iy = 2*oy + r - 1;
        bool yok = (unsigned)iy < 128u;
        const float* inrow = in + ((size_t)(b*128) + iy)*128*128;
        for (int cs = 0; cs < 4; ++cs) {
            __syncthreads();
            for (int i = tid; i < 130*32; i += 256) {
                int ixl = i >> 5, ci = i & 31;
                int ix = ixl - 1;
                xs[ixl*33 + ci] = (yok && (unsigned)ix < 128u)
                    ? inrow[(size_t)ix*128 + cs*32 + ci] : 0.f;
            }
            for (int t = 0; t < 4; ++t) {
                __syncthreads();
                const float* wsrc = w + ((size_t)((r*4 + t)*128 + cs*32))*128;
                for (int i = tid; i < 4096; i += 256) wb[i] = wsrc[i];
                __syncthreads();
                #pragma unroll 8
                for (int ci = 0; ci < 32; ++ci) {
                    float a_[4];
                    #pragma unroll
                    for (int j = 0; j < 4; ++j) a_[j] = xs[(2*(p0+j) + t)*33 + ci];
                    float4 b0 = *(const float4*)&wb[ci*128 + c0a];
                    float4 b1 = *(const float4*)&wb[ci*128 + c0b];
                    #pragma unroll
                    for (int j = 0; j < 4; ++j) {
                        acc[j][0] += a_[j]*b0.x; acc[j][1] += a_[j]*b0.y;
                        acc[j][2] += a_[j]*b0.z; acc[j][3] += a_[j]*b0.w;
                        acc[j][4] += a_[j]*b1.x; acc[j][5] += a_[j]*b1.y;
                        acc[j][6] += a_[j]*b1.z; acc[j][7] += a_[j]*b1.w;
                    }
                }
            }
        }
    }
    float bv[8];
    #pragma unroll
    for (int i = 0; i < 4; ++i) { bv[i] = bias[c0a+i]; bv[4+i] = bias[c0b+i]; }
    #pragma unroll
    for (int j = 0; j < 4; ++j) {
        float* o = out + (((size_t)(b*64) + oy)*64 + (p0 + j))*128;
        float4 va, vb;
        va.x = gelu_f(acc[j][0]+bv[0]); va.y = gelu_f(acc[j][1]+bv[1]);
        va.z = gelu_f(acc[j][2]+bv[2]); va.w = gelu_f(acc[j][3]+bv[3]);
        vb.x = gelu_f(acc[j][4]+bv[4]); vb.y = gelu_f(acc[j][5]+bv[5]);
        vb.z = gelu_f(acc[j][6]+bv[6]); vb.w = gelu_f(acc[j][7]+bv[7]);
        *(float4*)&o[c0a] = va;
        *(float4*)&o[c0b] = vb;
    }
}

// ---------------- conv3 (1x1, 128->64, +bias, no act): h2 -> z_e [65536,64]
__global__ __launch_bounds__(256) void k_conv3(const float* __restrict__ in,
        const float* __restrict__ w, const float* __restrict__ bias,
        float* __restrict__ out) {
    __shared__ __align__(16) float xs[128*33];
    __shared__ __align__(16) float wb[32*64];
    const int tid = threadIdx.x;
    const size_t pix0 = (size_t)blockIdx.x * 128;
    const int cg = tid & 7, pg = tid >> 3;
    const int c0a = cg*4, c0b = 32 + cg*4;
    const int p0 = pg*4;

    float acc[4][8];
    #pragma unroll
    for (int j = 0; j < 4; ++j)
        #pragma unroll
        for (int i = 0; i < 8; ++i) acc[j][i] = 0.f;

    for (int cs = 0; cs < 4; ++cs) {
        __syncthreads();
        for (int i = tid; i < 4096; i += 256) {
            int p = i >> 5, ci = i & 31;
            xs[p*33 + ci] = in[(pix0 + p)*128 + cs*32 + ci];
        }
        for (int i = tid; i < 2048; i += 256) {
            int ci = i >> 6, c = i & 63;
            wb[i] = w[(size_t)(cs*32 + ci)*64 + c];
        }
        __syncthreads();
        #pragma unroll 8
        for (int ci = 0; ci < 32; ++ci) {
            float a_[4];
            #pragma unroll
            for (int j = 0; j < 4; ++j) a_[j] = xs[(p0+j)*33 + ci];
            float4 b0 = *(const float4*)&wb[ci*64 + c0a];
            float4 b1 = *(const float4*)&wb[ci*64 + c0b];
            #pragma unroll
            for (int j = 0; j < 4; ++j) {
                acc[j][0] += a_[j]*b0.x; acc[j][1] += a_[j]*b0.y;
                acc[j][2] += a_[j]*b0.z; acc[j][3] += a_[j]*b0.w;
                acc[j][4] += a_[j]*b1.x; acc[j][5] += a_[j]*b1.y;
                acc[j][6] += a_[j]*b1.z; acc[j][7] += a_[j]*b1.w;
            }
        }
    }
    #pragma unroll
    for (int j = 0; j < 4; ++j) {
        float* o = out + (pix0 + p0 + j)*64;
        float4 va, vb;
        va.x = acc[j][0]+bias[c0a+0]; va.y = acc[j][1]+bias[c0a+1];
        va.z = acc[j][2]+bias[c0a+2]; va.w = acc[j][3]+bias[c0a+3];
        vb.x = acc[j][4]+bias[c0b+0]; vb.y = acc[j][5]+bias[c0b+1];
        vb.z = acc[j][6]+bias[c0b+2]; vb.w = acc[j][7]+bias[c0b+3];
        *(float4*)&o[c0a] = va;
        *(float4*)&o[c0b] = vb;
    }
}

// ---------------- VQ (unchanged, f32, ref formula dist = z2+e2-2*dot)
__global__ __launch_bounds__(256) void k_vq(const float* __restrict__ ze,
        const float* __restrict__ cb, float* __restrict__ zq,
        float* __restrict__ tok, float* __restrict__ loss_acc) {
    __shared__ __align__(16) float zs[64*65];
    __shared__ __align__(16) float bt[64*132];
    __shared__ float es[128];
    __shared__ float z2s[64];
    __shared__ float rmin[64*16];
    __shared__ int   ridx[64*16];
    __shared__ int   widx[64];
    __shared__ float wsum[4];
    const int tid = threadIdx.x;
    const size_t tok0 = (size_t)blockIdx.x * 64;
    const int cg = tid & 15, pg = tid >> 4;
    const int k0a = cg*4, k0b = 64 + cg*4;
    const int t0 = pg*4;

    for (int i = tid; i < 4096; i += 256) {
        int tk = i >> 6, d = i & 63;
        zs[tk*65 + d] = ze[(tok0 + tk)*64 + d];
    }
    __syncthreads();
    if (tid < 64) {
        float s = 0.f;
        for (int d = 0; d < 64; ++d) { float v = zs[tid*65 + d]; s += v*v; }
        z2s[tid] = s;
    }

    float bmin[4] = {3.4e38f,3.4e38f,3.4e38f,3.4e38f};
    int   bidx[4] = {0,0,0,0};

    for (int ch = 0; ch < 8; ++ch) {
        __syncthreads();
        for (int i = tid; i < 8192; i += 256) {
            int k = i >> 6, d = i & 63;
            bt[d*132 + k] = cb[((size_t)(ch*128) + k)*64 + d];
        }
        __syncthreads();
        if (tid < 128) {
            float s = 0.f;
            for (int d = 0; d < 64; ++d) { float v = bt[d*132 + tid]; s += v*v; }
            es[tid] = s;
        }
        __syncthreads();
        float acc[4][8];
        #pragma unroll
        for (int j = 0; j < 4; ++j)
            #pragma unroll
            for (int i = 0; i < 8; ++i) acc[j][i] = 0.f;
        #pragma unroll 4
        for (int d = 0; d < 64; ++d) {
            float a_[4];
            #pragma unroll
            for (int j = 0; j < 4; ++j) a_[j] = zs[(t0+j)*65 + d];
            float4 b0 = *(const float4*)&bt[d*132 + k0a];
            float4 b1 = *(const float4*)&bt[d*132 + k0b];
            #pragma unroll
            for (int j = 0; j < 4; ++j) {
                acc[j][0] += a_[j]*b0.x; acc[j][1] += a_[j]*b0.y;
                acc[j][2] += a_[j]*b0.z; acc[j][3] += a_[j]*b0.w;
                acc[j][4] += a_[j]*b1.x; acc[j][5] += a_[j]*b1.y;
                acc[j][6] += a_[j]*b1.z; acc[j][7] += a_[j]*b1.w;
            }
        }
        #pragma unroll
        for (int j = 0; j < 4; ++j) {
            float z2 = z2s[t0+j];
            #pragma unroll
            for (int i = 0; i < 4; ++i) {
                float dist = (z2 + es[k0a+i]) - 2.f*acc[j][i];
                int idx = ch*128 + k0a + i;
                if (dist < bmin[j]) { bmin[j] = dist; bidx[j] = idx; }
            }
            #pragma unroll
            for (int i = 0; i < 4; ++i) {
                float dist = (z2 + es[k0b+i]) - 2.f*acc[j][4+i];
                int idx = ch*128 + k0b + i;
                if (dist < bmin[j]) { bmin[j] = dist; bidx[j] = idx; }
            }
        }
    }
    #pragma unroll
    for (int j = 0; j < 4; ++j) {
        rmin[(t0+j)*16 + cg] = bmin[j];
        ridx[(t0+j)*16 + cg] = bidx[j];
    }
    __syncthreads();
    if (tid < 64) {
        float bv = rmin[tid*16]; int bi = ridx[tid*16];
        for (int g = 1; g < 16; ++g) {
            float v = rmin[tid*16 + g]; int ii = ridx[tid*16 + g];
            if (v < bv || (v == bv && ii < bi)) { bv = v; bi = ii; }
        }
        widx[tid] = bi;
        tok[tok0 + tid] = (float)bi;
    }
    __syncthreads();
    float lsum = 0.f;
    for (int i = tid; i < 4096; i += 256) {
        int tk = i >> 6, d = i & 63;
        float v = cb[(size_t)widx[tk]*64 + d];
        zq[(tok0 + tk)*64 + d] = v;
        float diff = v - zs[tk*65 + d];
        lsum += diff*diff;
    }
    #pragma unroll
    for (int off = 32; off > 0; off >>= 1) lsum += __shfl_down(lsum, off, 64);
    if ((tid & 63) == 0) wsum[tid >> 6] = lsum;
    __syncthreads();
    if (tid == 0) atomicAdd(loss_acc, wsum[0]+wsum[1]+wsum[2]+wsum[3]);
}

// ---------------- weight convert: dw2[rt][ci][co] f32 -> wtb[rt][co][ci] bf16
__global__ __launch_bounds__(256) void k_wcvt(const float* __restrict__ dw2,
        unsigned short* __restrict__ wtb) {
    int i = blockIdx.x*256 + threadIdx.x;        // 262144 total
    int rt = i >> 14, rem = i & 16383;
    int co = rem >> 7, ci = rem & 127;
    wtb[i] = f2bf(dw2[(size_t)rt*16384 + (size_t)ci*128 + co]);
}

// ---------------- convT1: z_q[16,64,64,64] -> g1 bf16 [16,128,128,128], GELU.
__global__ __launch_bounds__(256) void k_convt1(const float* __restrict__ zq,
        const float* __restrict__ w, const float* __restrict__ bias,
        unsigned short* __restrict__ out) {
    __shared__ __align__(16) float as_[64*65];
    __shared__ __align__(16) float wb[64*128];
    const int tid = threadIdx.x;
    const int par = blockIdx.x & 1;
    const int oy  = (blockIdx.x >> 1) & 127;
    const int b   = blockIdx.x >> 8;
    const int cg = tid & 15, pg = tid >> 4;
    const int c0a = cg*4, c0b = 64 + cg*4;
    const int p0 = pg*4;
    const int ey = oy & 1, q = oy >> 1;

    float acc[4][8];
    #pragma unroll
    for (int j = 0; j < 4; ++j)
        #pragma unroll
        for (int i = 0; i < 8; ++i) acc[j][i] = 0.f;

    for (int tap = 0; tap < 4; ++tap) {
        int rr = tap >> 1, tt = tap & 1;
        int r = ey + rr*2, t = par + tt*2;
        int iy = q + ey - 1 + rr;
        bool yok = (unsigned)iy < 64u;
        const float* inrow = zq + ((size_t)(b*64) + iy)*64*64;
        __syncthreads();
        for (int i = tid; i < 4096; i += 256) {
            int p = i >> 6, ci = i & 63;
            int ix = p + par - 1 + tt;
            as_[p*65 + ci] = (yok && (unsigned)ix < 64u)
                ? inrow[(size_t)ix*64 + ci] : 0.f;
        }
        const float* wsrc = w + (size_t)((r*4 + t)*64)*128;
        for (int i = tid; i < 8192; i += 256) wb[i] = wsrc[i];
        __syncthreads();
        #pragma unroll 8
        for (int ci = 0; ci < 64; ++ci) {
            float a_[4];
            #pragma unroll
            for (int j = 0; j < 4; ++j) a_[j] = as_[(p0+j)*65 + ci];
            float4 b0 = *(const float4*)&wb[ci*128 + c0a];
            float4 b1 = *(const float4*)&wb[ci*128 + c0b];
            #pragma unroll
            for (int j = 0; j < 4; ++j) {
                acc[j][0] += a_[j]*b0.x; acc[j][1] += a_[j]*b0.y;
                acc[j][2] += a_[j]*b0.z; acc[j][3] += a_[j]*b0.w;
                acc[j][4] += a_[j]*b1.x; acc[j][5] += a_[j]*b1.y;
                acc[j][6] += a_[j]*b1.z; acc[j][7] += a_[j]*b1.w;
            }
        }
    }
    float bv[8];
    #pragma unroll
    for (int i = 0; i < 4; ++i) { bv[i] = bias[c0a+i]; bv[4+i] = bias[c0b+i]; }
    #pragma unroll
    for (int j = 0; j < 4; ++j) {
        int ox = par + 2*(p0 + j);
        unsigned short* o = out + (((size_t)(b*128) + oy)*128 + ox)*128;
        ushort4 va, vb;
        va.x = f2bf(gelu_f(acc[j][0]+bv[0])); va.y = f2bf(gelu_f(acc[j][1]+bv[1]));
        va.z = f2bf(gelu_f(acc[j][2]+bv[2])); va.w = f2bf(gelu_f(acc[j][3]+bv[3]));
        vb.x = f2bf(gelu_f(acc[j][4]+bv[4])); vb.y = f2bf(gelu_f(acc[j][5]+bv[5]));
        vb.z = f2bf(gelu_f(acc[j][6]+bv[6])); vb.w = f2bf(gelu_f(acc[j][7]+bv[7]));
        *(ushort4*)&o[c0a] = va;
        *(ushort4*)&o[c0b] = vb;
    }
}

// ---------------- convT2 (bf16 MFMA) + fused final 1x1: g1b -> x_rec
// Per block (b,oy,par): M=128 px, N=128 co, K=512 (4 taps x 128 ci).
// LDS panels [kc][128][32] bf16 (m97 layout). 4 waves in 2x2; 4x4 frags/wave.
__global__ __launch_bounds__(256) void k_convt2(const unsigned short* __restrict__ g1b,
        const unsigned short* __restrict__ wtb, const float* __restrict__ b2,
        const float* __restrict__ w3, const float* __restrict__ b3,
        float* __restrict__ xrec) {
    union SM {
        struct { unsigned short A[4*128*32]; unsigned short B[4*128*32]; } s; // 64 KB
        float red[128*32*3];                                                  // 48 KB
    };
    __shared__ __align__(16) union SM sm;
    const int tid  = threadIdx.x;
    const int par  = blockIdx.x & 1;
    const int oy   = (blockIdx.x >> 1) & 255;
    const int b    = blockIdx.x >> 9;
    const int lane = tid & 63, l15 = lane & 15, q = lane >> 4;
    const int wid  = tid >> 6, wm = wid >> 1, wn = wid & 1;
    const int ey = oy & 1, qy = oy >> 1;

    f32x4 acc[4][4];
    #pragma unroll
    for (int fm = 0; fm < 4; ++fm)
        #pragma unroll
        for (int fn = 0; fn < 4; ++fn) acc[fm][fn] = (f32x4){0.f,0.f,0.f,0.f};

    for (int tap = 0; tap < 4; ++tap) {
        int rr = tap >> 1, tt = tap & 1;
        int r = ey + rr*2, t = par + tt*2;
        int iy = qy + ey - 1 + rr;
        bool yok = (unsigned)iy < 128u;
        const unsigned short* arow = g1b + ((size_t)(b*128) + (yok?iy:0))*128*128;
        const unsigned short* brow = wtb + (size_t)(r*4 + t)*16384;
        __syncthreads();
        // stage A: 128 px x 128 ci bf16, panel layout [ci>>5][px][ci&31]
        for (int i = tid; i < 2048; i += 256) {
            int px = i >> 4, cc = i & 15;
            int ci0 = cc*8;
            int ix = px + par - 1 + tt;
            uint4 v = make_uint4(0,0,0,0);
            if (yok && (unsigned)ix < 128u)
                v = *(const uint4*)(arow + (size_t)ix*128 + ci0);
            *(uint4*)&sm.s.A[((cc>>2)*128 + px)*32 + (ci0 & 31)] = v;
        }
        // stage Bt: 128 co x 128 ci bf16, panel layout [ci>>5][co][ci&31]
        for (int i = tid; i < 2048; i += 256) {
            int co = i >> 4, cc = i & 15;
            int ci0 = cc*8;
            uint4 v = *(const uint4*)(brow + (size_t)co*128 + ci0);
            *(uint4*)&sm.s.B[((cc>>2)*128 + co)*32 + (ci0 & 31)] = v;
        }
        __syncthreads();
        #pragma unroll
        for (int kc = 0; kc < 4; ++kc) {
            short8 af[4], bf[4];
            #pragma unroll
            for (int fm = 0; fm < 4; ++fm)
                af[fm] = *(const short8*)&sm.s.A[((kc*128 + wm*64 + fm*16 + l15)*32) + q*8];
            #pragma unroll
            for (int fn = 0; fn < 4; ++fn)
                bf[fn] = *(const short8*)&sm.s.B[((kc*128 + wn*64 + fn*16 + l15)*32) + q*8];
            #pragma unroll
            for (int fm = 0; fm < 4; ++fm)
                #pragma unroll
                for (int fn = 0; fn < 4; ++fn)
                    acc[fm][fn] = __builtin_amdgcn_mfma_f32_16x16x32_bf16(
                        af[fm], bf[fn], acc[fm][fn], 0, 0, 0);
        }
    }

    // epilogue: GELU(acc + b2), project 128->3, reduce across co in LDS
    float b2v[4];
    float w3v[4][3];
    #pragma unroll
    for (int fn = 0; fn < 4; ++fn) {
        int co = wn*64 + fn*16 + l15;
        b2v[fn] = b2[co];
        w3v[fn][0] = w3[co*3+0]; w3v[fn][1] = w3[co*3+1]; w3v[fn][2] = w3[co*3+2];
    }
    __syncthreads();
    #pragma unroll
    for (int fm = 0; fm < 4; ++fm) {
        #pragma unroll
        for (int rg = 0; rg < 4; ++rg) {
            int px = wm*64 + fm*16 + q*4 + rg;
            float s0 = 0.f, s1 = 0.f, s2 = 0.f;
            #pragma unroll
            for (int fn = 0; fn < 4; ++fn) {
                float y = gelu_f(acc[fm][fn][rg] + b2v[fn]);
                s0 += y*w3v[fn][0]; s1 += y*w3v[fn][1]; s2 += y*w3v[fn][2];
            }
            int slot = wn*16 + l15;
            sm.red[(px*32 + slot)*3 + 0] = s0;
            sm.red[(px*32 + slot)*3 + 1] = s1;
            sm.red[(px*32 + slot)*3 + 2] = s2;
        }
    }
    __syncthreads();
    for (int o = tid; o < 384; o += 256) {
        int px = o/3, jj = o - px*3;
        float s = b3[jj];
        #pragma unroll
        for (int g = 0; g < 32; ++g) s += sm.red[(px*32 + g)*3 + jj];
        xrec[(((size_t)(b*256) + oy)*256 + (par + 2*px))*3 + jj] = s;
    }
}

__global__ void k_zero(float* p) { if (threadIdx.x == 0) p[0] = 0.f; }

__global__ void k_finalize(const float* __restrict__ loss_acc, float* __restrict__ o) {
    if (threadIdx.x == 0) {
        float v = loss_acc[0] * (1.0f/4194304.0f);
        o[0] = v;
        o[1] = v;
    }
}

extern "C" void kernel_launch(void* const* d_in, const int* in_sizes, int n_in,
                              void* d_out, int out_size, void* d_ws, size_t ws_size,
                              hipStream_t stream) {
    (void)in_sizes; (void)n_in; (void)out_size; (void)ws_size;
    const float* x   = (const float*)d_in[0];
    const float* ew1 = (const float*)d_in[1];
    const float* eb1 = (const float*)d_in[2];
    const float* ew2 = (const float*)d_in[3];
    const float* eb2 = (const float*)d_in[4];
    const float* ew3 = (const float*)d_in[5];
    const float* eb3 = (const float*)d_in[6];
    const float* cb  = (const float*)d_in[7];
    const float* dw1 = (const float*)d_in[8];
    const float* db1 = (const float*)d_in[9];
    const float* dw2 = (const float*)d_in[10];
    const float* db2 = (const float*)d_in[11];
    const float* dw3 = (const float*)d_in[12];
    const float* db3 = (const float*)d_in[13];

    float* ws   = (float*)d_ws;
    float* h1   = ws;                       // 33,554,432 f; later g1b (bf16) aliases
    float* h2   = h1 + 33554432;            //  8,388,608 f
    float* ze   = h2 + 8388608;             //  4,194,304 f; later wtb (bf16) aliases
    float* zq   = ze + 4194304;             //  4,194,304 f
    float* lacc = zq + 4194304;             //          1 f
    unsigned short* g1b = (unsigned short*)h1;   // dead after conv2
    unsigned short* wtb = (unsigned short*)ze;   // dead after vq; 262144 bf16

    float* xrec = (float*)d_out;            // 3,145,728 f
    float* tokf = xrec + 3145728;           //    65,536 f
    float* loss = tokf + 65536;             //         2 f

    k_conv1   <<<4096, 256, 0, stream>>>(x, ew1, eb1, h1);
    k_conv2   <<<1024, 256, 0, stream>>>(h1, ew2, eb2, h2);
    k_conv3   <<< 512, 256, 0, stream>>>(h2, ew3, eb3, ze);
    k_zero    <<<   1,  64, 0, stream>>>(lacc);
    k_vq      <<<1024, 256, 0, stream>>>(ze, cb, zq, tokf, lacc);
    k_wcvt    <<<1024, 256, 0, stream>>>(dw2, wtb);             // ze now dead
    k_convt1  <<<4096, 256, 0, stream>>>(zq, dw1, db1, g1b);    // h1 now dead
    k_convt2  <<<8192, 256, 0, stream>>>(g1b, wtb, db2, dw3, db3, xrec);
    k_finalize<<<   1,  64, 0, stream>>>(lacc, loss);
}

// Round 4
// 998.869 us; speedup vs baseline: 2.9743x; 1.5071x over previous
//
#include <hip/hip_runtime.h>
#include <math.h>

// Shapes: B=16, x[16,256,256,3], h1[16,128,128,128], h2[16,64,64,128],
// z_e/z_q[65536,64], g1[16,128,128,128](bf16), x_rec[16,256,256,3], K=1024.
//
// R4: conv2 -> split-bf16 (3xbf16) MFMA: a=ah+al, b=bh+bl, acc = ah*bh+al*bh+ah*bl.
// Residual ~2^-17 rel -> tokens stay exact. conv1 writes h1 as hi/lo bf16 planes.
// convt1 -> plain bf16 MFMA (decoder side; z_q stored bf16 by k_vq).

typedef __attribute__((ext_vector_type(8))) short short8;
typedef __attribute__((ext_vector_type(4))) float f32x4;

__device__ __forceinline__ float gelu_f(float x) {
    float x3 = x*x*x;
    return 0.5f*x*(1.0f + tanhf(0.7978845608028654f*(x + 0.044715f*x3)));
}

__device__ __forceinline__ unsigned short f2bf(float f) {
    unsigned int u = __float_as_uint(f);
    u = (u + 0x7FFFu + ((u >> 16) & 1u)) >> 16;   // RNE
    return (unsigned short)u;
}
__device__ __forceinline__ float bf2f(unsigned short h) {
    return __uint_as_float(((unsigned int)h) << 16);
}

// ---------------- conv1: x[16,256,256,3] -> h1 hi/lo bf16 planes, 4x4 s2 SAME, GELU
__global__ __launch_bounds__(256) void k_conv1(const float* __restrict__ x,
        const float* __restrict__ w, const float* __restrict__ bias,
        unsigned short* __restrict__ outh, unsigned short* __restrict__ outl) {
    __shared__ __align__(16) float ws[48*128];
    __shared__ __align__(16) float xs[4][390];
    const int tid = threadIdx.x;
    const int blk = blockIdx.x;
    const int oxt = blk & 1;
    const int oy  = (blk >> 1) & 127;
    const int b   = blk >> 8;
    const int cg = tid & 15, pg = tid >> 4;
    const int c0a = cg*4, c0b = 64 + cg*4;
    const int p0 = pg*4;
    const int ox0 = oxt*64;

    for (int i = tid; i < 6144; i += 256) ws[i] = w[i];
    for (int r = 0; r < 4; ++r) {
        int iy = 2*oy + r - 1;
        bool yok = (unsigned)iy < 256u;
        const float* xrow = x + ((size_t)(b*256) + iy)*256*3;
        for (int i = tid; i < 390; i += 256) {
            int ixl = i/3, ci = i - ixl*3;
            int ix = 2*ox0 - 1 + ixl;
            xs[r][i] = (yok && (unsigned)ix < 256u) ? xrow[(size_t)ix*3 + ci] : 0.f;
        }
    }
    __syncthreads();

    float acc[4][8];
    #pragma unroll
    for (int j = 0; j < 4; ++j)
        #pragma unroll
        for (int i = 0; i < 8; ++i) acc[j][i] = 0.f;

    #pragma unroll 6
    for (int pos = 0; pos < 48; ++pos) {
        int r = pos/12, tc = pos - r*12;
        int t = tc/3,  ci = tc - t*3;
        float4 w0 = *(const float4*)&ws[pos*128 + c0a];
        float4 w1 = *(const float4*)&ws[pos*128 + c0b];
        #pragma unroll
        for (int j = 0; j < 4; ++j) {
            float av = xs[r][(2*(p0+j) + t)*3 + ci];
            acc[j][0] += av*w0.x; acc[j][1] += av*w0.y;
            acc[j][2] += av*w0.z; acc[j][3] += av*w0.w;
            acc[j][4] += av*w1.x; acc[j][5] += av*w1.y;
            acc[j][6] += av*w1.z; acc[j][7] += av*w1.w;
        }
    }
    float bv[8];
    #pragma unroll
    for (int i = 0; i < 4; ++i) { bv[i] = bias[c0a+i]; bv[4+i] = bias[c0b+i]; }
    #pragma unroll
    for (int j = 0; j < 4; ++j) {
        int ox = ox0 + p0 + j;
        size_t base = (((size_t)(b*128) + oy)*128 + ox)*128;
        ushort4 ha, hb, la, lb;
        float y;
        y = gelu_f(acc[j][0]+bv[0]); ha.x = f2bf(y); la.x = f2bf(y - bf2f(ha.x));
        y = gelu_f(acc[j][1]+bv[1]); ha.y = f2bf(y); la.y = f2bf(y - bf2f(ha.y));
        y = gelu_f(acc[j][2]+bv[2]); ha.z = f2bf(y); la.z = f2bf(y - bf2f(ha.z));
        y = gelu_f(acc[j][3]+bv[3]); ha.w = f2bf(y); la.w = f2bf(y - bf2f(ha.w));
        y = gelu_f(acc[j][4]+bv[4]); hb.x = f2bf(y); lb.x = f2bf(y - bf2f(hb.x));
        y = gelu_f(acc[j][5]+bv[5]); hb.y = f2bf(y); lb.y = f2bf(y - bf2f(hb.y));
        y = gelu_f(acc[j][6]+bv[6]); hb.z = f2bf(y); lb.z = f2bf(y - bf2f(hb.z));
        y = gelu_f(acc[j][7]+bv[7]); hb.w = f2bf(y); lb.w = f2bf(y - bf2f(hb.w));
        *(ushort4*)&outh[base + c0a] = ha;
        *(ushort4*)&outh[base + c0b] = hb;
        *(ushort4*)&outl[base + c0a] = la;
        *(ushort4*)&outl[base + c0b] = lb;
    }
}

// ---------------- conv2 (split-bf16 MFMA): h1 hi/lo -> h2[16,64,64,128] f32, GELU
// Block (b, oy-pair): M=128 px (2 rows of 64), N=128 co, K=16 taps x 128 ci x 3 terms.
__global__ __launch_bounds__(256) void k_conv2m(const unsigned short* __restrict__ h1h,
        const unsigned short* __restrict__ h1l,
        const unsigned short* __restrict__ w2h, const unsigned short* __restrict__ w2l,
        const float* __restrict__ bias, float* __restrict__ out) {
    __shared__ __align__(16) unsigned short Ah[2*128*32];
    __shared__ __align__(16) unsigned short Al[2*128*32];
    __shared__ __align__(16) unsigned short Bh[2*128*32];
    __shared__ __align__(16) unsigned short Bl[2*128*32];
    const int tid = threadIdx.x;
    const int yy = blockIdx.x & 31;
    const int b  = blockIdx.x >> 5;
    const int oy0 = yy*2;
    const int lane = tid & 63, l15 = lane & 15, q = lane >> 4;
    const int wid = tid >> 6, wm = wid >> 1, wn = wid & 1;

    f32x4 acc[4][4];
    #pragma unroll
    for (int fm = 0; fm < 4; ++fm)
        #pragma unroll
        for (int fn = 0; fn < 4; ++fn) acc[fm][fn] = (f32x4){0.f,0.f,0.f,0.f};

    for (int tap = 0; tap < 16; ++tap) {
        int r = tap >> 2, t = tap & 3;
        for (int cs = 0; cs < 2; ++cs) {
            __syncthreads();
            for (int i = tid; i < 1024; i += 256) {
                int px = i >> 3, cc = i & 7, ci0 = cc*8;
                int oy = oy0 + (px >> 6), ox = px & 63;
                int iy = 2*oy + r - 1, ix = 2*ox + t - 1;
                uint4 vh = make_uint4(0,0,0,0), vl = make_uint4(0,0,0,0);
                if ((unsigned)iy < 128u && (unsigned)ix < 128u) {
                    size_t off = (((size_t)(b*128) + iy)*128 + ix)*128 + cs*64 + ci0;
                    vh = *(const uint4*)(h1h + off);
                    vl = *(const uint4*)(h1l + off);
                }
                int idx = ((cc>>2)*128 + px)*32 + (ci0 & 31);
                *(uint4*)&Ah[idx] = vh;
                *(uint4*)&Al[idx] = vl;
            }
            for (int i = tid; i < 1024; i += 256) {
                int co = i >> 3, cc = i & 7, ci0 = cc*8;
                size_t off = ((size_t)tap*128 + co)*128 + cs*64 + ci0;
                uint4 vh = *(const uint4*)(w2h + off);
                uint4 vl = *(const uint4*)(w2l + off);
                int idx = ((cc>>2)*128 + co)*32 + (ci0 & 31);
                *(uint4*)&Bh[idx] = vh;
                *(uint4*)&Bl[idx] = vl;
            }
            __syncthreads();
            #pragma unroll
            for (int kc = 0; kc < 2; ++kc) {
                short8 ah[4], al[4], bh[4], bl[4];
                #pragma unroll
                for (int fm = 0; fm < 4; ++fm) {
                    int row = (kc*128 + wm*64 + fm*16 + l15)*32 + q*8;
                    ah[fm] = *(const short8*)&Ah[row];
                    al[fm] = *(const short8*)&Al[row];
                }
                #pragma unroll
                for (int fn = 0; fn < 4; ++fn) {
                    int row = (kc*128 + wn*64 + fn*16 + l15)*32 + q*8;
                    bh[fn] = *(const short8*)&Bh[row];
                    bl[fn] = *(const short8*)&Bl[row];
                }
                #pragma unroll
                for (int fm = 0; fm < 4; ++fm)
                    #pragma unroll
                    for (int fn = 0; fn < 4; ++fn) {
                        acc[fm][fn] = __builtin_amdgcn_mfma_f32_16x16x32_bf16(
                            ah[fm], bh[fn], acc[fm][fn], 0, 0, 0);
                        acc[fm][fn] = __builtin_amdgcn_mfma_f32_16x16x32_bf16(
                            al[fm], bh[fn], acc[fm][fn], 0, 0, 0);
                        acc[fm][fn] = __builtin_amdgcn_mfma_f32_16x16x32_bf16(
                            ah[fm], bl[fn], acc[fm][fn], 0, 0, 0);
                    }
            }
        }
    }
    float bv[4];
    #pragma unroll
    for (int fn = 0; fn < 4; ++fn) bv[fn] = bias[wn*64 + fn*16 + l15];
    #pragma unroll
    for (int fm = 0; fm < 4; ++fm)
        #pragma unroll
        for (int rg = 0; rg < 4; ++rg) {
            int px = wm*64 + fm*16 + q*4 + rg;
            int oy = oy0 + (px >> 6), ox = px & 63;
            float* o = out + (((size_t)(b*64) + oy)*64 + ox)*128;
            #pragma unroll
            for (int fn = 0; fn < 4; ++fn)
                o[wn*64 + fn*16 + l15] = gelu_f(acc[fm][fn][rg] + bv[fn]);
        }
}

// ---------------- conv3 (1x1, 128->64, f32): h2 -> z_e [65536,64]
__global__ __launch_bounds__(256) void k_conv3(const float* __restrict__ in,
        const float* __restrict__ w, const float* __restrict__ bias,
        float* __restrict__ out) {
    __shared__ __align__(16) float xs[128*33];
    __shared__ __align__(16) float wb[32*64];
    const int tid = threadIdx.x;
    const size_t pix0 = (size_t)blockIdx.x * 128;
    const int cg = tid & 7, pg = tid >> 3;
    const int c0a = cg*4, c0b = 32 + cg*4;
    const int p0 = pg*4;

    float acc[4][8];
    #pragma unroll
    for (int j = 0; j < 4; ++j)
        #pragma unroll
        for (int i = 0; i < 8; ++i) acc[j][i] = 0.f;

    for (int cs = 0; cs < 4; ++cs) {
        __syncthreads();
        for (int i = tid; i < 4096; i += 256) {
            int p = i >> 5, ci = i & 31;
            xs[p*33 + ci] = in[(pix0 + p)*128 + cs*32 + ci];
        }
        for (int i = tid; i < 2048; i += 256) {
            int ci = i >> 6, c = i & 63;
            wb[i] = w[(size_t)(cs*32 + ci)*64 + c];
        }
        __syncthreads();
        #pragma unroll 8
        for (int ci = 0; ci < 32; ++ci) {
            float a_[4];
            #pragma unroll
            for (int j = 0; j < 4; ++j) a_[j] = xs[(p0+j)*33 + ci];
            float4 b0 = *(const float4*)&wb[ci*64 + c0a];
            float4 b1 = *(const float4*)&wb[ci*64 + c0b];
            #pragma unroll
            for (int j = 0; j < 4; ++j) {
                acc[j][0] += a_[j]*b0.x; acc[j][1] += a_[j]*b0.y;
                acc[j][2] += a_[j]*b0.z; acc[j][3] += a_[j]*b0.w;
                acc[j][4] += a_[j]*b1.x; acc[j][5] += a_[j]*b1.y;
                acc[j][6] += a_[j]*b1.z; acc[j][7] += a_[j]*b1.w;
            }
        }
    }
    #pragma unroll
    for (int j = 0; j < 4; ++j) {
        float* o = out + (pix0 + p0 + j)*64;
        float4 va, vb;
        va.x = acc[j][0]+bias[c0a+0]; va.y = acc[j][1]+bias[c0a+1];
        va.z = acc[j][2]+bias[c0a+2]; va.w = acc[j][3]+bias[c0a+3];
        vb.x = acc[j][4]+bias[c0b+0]; vb.y = acc[j][5]+bias[c0b+1];
        vb.z = acc[j][6]+bias[c0b+2]; vb.w = acc[j][7]+bias[c0b+3];
        *(float4*)&o[c0a] = va;
        *(float4*)&o[c0b] = vb;
    }
}

// ---------------- VQ: f32 (exact), writes z_q as bf16 for the decoder
__global__ __launch_bounds__(256) void k_vq(const float* __restrict__ ze,
        const float* __restrict__ cb, unsigned short* __restrict__ zqb,
        float* __restrict__ tok, float* __restrict__ loss_acc) {
    __shared__ __align__(16) float zs[64*65];
    __shared__ __align__(16) float bt[64*132];
    __shared__ float es[128];
    __shared__ float z2s[64];
    __shared__ float rmin[64*16];
    __shared__ int   ridx[64*16];
    __shared__ int   widx[64];
    __shared__ float wsum[4];
    const int tid = threadIdx.x;
    const size_t tok0 = (size_t)blockIdx.x * 64;
    const int cg = tid & 15, pg = tid >> 4;
    const int k0a = cg*4, k0b = 64 + cg*4;
    const int t0 = pg*4;

    for (int i = tid; i < 4096; i += 256) {
        int tk = i >> 6, d = i & 63;
        zs[tk*65 + d] = ze[(tok0 + tk)*64 + d];
    }
    __syncthreads();
    if (tid < 64) {
        float s = 0.f;
        for (int d = 0; d < 64; ++d) { float v = zs[tid*65 + d]; s += v*v; }
        z2s[tid] = s;
    }

    float bmin[4] = {3.4e38f,3.4e38f,3.4e38f,3.4e38f};
    int   bidx[4] = {0,0,0,0};

    for (int ch = 0; ch < 8; ++ch) {
        __syncthreads();
        for (int i = tid; i < 8192; i += 256) {
            int k = i >> 6, d = i & 63;
            bt[d*132 + k] = cb[((size_t)(ch*128) + k)*64 + d];
        }
        __syncthreads();
        if (tid < 128) {
            float s = 0.f;
            for (int d = 0; d < 64; ++d) { float v = bt[d*132 + tid]; s += v*v; }
            es[tid] = s;
        }
        __syncthreads();
        float acc[4][8];
        #pragma unroll
        for (int j = 0; j < 4; ++j)
            #pragma unroll
            for (int i = 0; i < 8; ++i) acc[j][i] = 0.f;
        #pragma unroll 4
        for (int d = 0; d < 64; ++d) {
            float a_[4];
            #pragma unroll
            for (int j = 0; j < 4; ++j) a_[j] = zs[(t0+j)*65 + d];
            float4 b0 = *(const float4*)&bt[d*132 + k0a];
            float4 b1 = *(const float4*)&bt[d*132 + k0b];
            #pragma unroll
            for (int j = 0; j < 4; ++j) {
                acc[j][0] += a_[j]*b0.x; acc[j][1] += a_[j]*b0.y;
                acc[j][2] += a_[j]*b0.z; acc[j][3] += a_[j]*b0.w;
                acc[j][4] += a_[j]*b1.x; acc[j][5] += a_[j]*b1.y;
                acc[j][6] += a_[j]*b1.z; acc[j][7] += a_[j]*b1.w;
            }
        }
        #pragma unroll
        for (int j = 0; j < 4; ++j) {
            float z2 = z2s[t0+j];
            #pragma unroll
            for (int i = 0; i < 4; ++i) {
                float dist = (z2 + es[k0a+i]) - 2.f*acc[j][i];
                int idx = ch*128 + k0a + i;
                if (dist < bmin[j]) { bmin[j] = dist; bidx[j] = idx; }
            }
            #pragma unroll
            for (int i = 0; i < 4; ++i) {
                float dist = (z2 + es[k0b+i]) - 2.f*acc[j][4+i];
                int idx = ch*128 + k0b + i;
                if (dist < bmin[j]) { bmin[j] = dist; bidx[j] = idx; }
            }
        }
    }
    #pragma unroll
    for (int j = 0; j < 4; ++j) {
        rmin[(t0+j)*16 + cg] = bmin[j];
        ridx[(t0+j)*16 + cg] = bidx[j];
    }
    __syncthreads();
    if (tid < 64) {
        float bv = rmin[tid*16]; int bi = ridx[tid*16];
        for (int g = 1; g < 16; ++g) {
            float v = rmin[tid*16 + g]; int ii = ridx[tid*16 + g];
            if (v < bv || (v == bv && ii < bi)) { bv = v; bi = ii; }
        }
        widx[tid] = bi;
        tok[tok0 + tid] = (float)bi;
    }
    __syncthreads();
    float lsum = 0.f;
    for (int i = tid; i < 4096; i += 256) {
        int tk = i >> 6, d = i & 63;
        float v = cb[(size_t)widx[tk]*64 + d];
        zqb[(tok0 + tk)*64 + d] = f2bf(v);
        float diff = v - zs[tk*65 + d];
        lsum += diff*diff;
    }
    #pragma unroll
    for (int off = 32; off > 0; off >>= 1) lsum += __shfl_down(lsum, off, 64);
    if ((tid & 63) == 0) wsum[tid >> 6] = lsum;
    __syncthreads();
    if (tid == 0) atomicAdd(loss_acc, wsum[0]+wsum[1]+wsum[2]+wsum[3]);
}

// ---------------- weight prep kernels
// ew2 [r][t][ci=128][co=128] f32 -> hi/lo bf16 [rt][co][ci]
__global__ __launch_bounds__(256) void k_wsplit2(const float* __restrict__ w,
        unsigned short* __restrict__ hi, unsigned short* __restrict__ lo) {
    int i = blockIdx.x*256 + threadIdx.x;        // 262144
    int rt = i >> 14, rem = i & 16383;
    int co = rem >> 7, ci = rem & 127;
    float v = w[((size_t)rt*128 + ci)*128 + co];
    unsigned short h = f2bf(v);
    hi[i] = h;
    lo[i] = f2bf(v - bf2f(h));
}
// dw2 [r][t][ci=128][co=128] -> bf16 [rt][co][ci]
__global__ __launch_bounds__(256) void k_wcvt2(const float* __restrict__ w,
        unsigned short* __restrict__ o) {
    int i = blockIdx.x*256 + threadIdx.x;        // 262144
    int rt = i >> 14, rem = i & 16383;
    int co = rem >> 7, ci = rem & 127;
    o[i] = f2bf(w[((size_t)rt*128 + ci)*128 + co]);
}
// dw1 [r][t][ci=64][co=128] -> bf16 [rt][co][ci=64]
__global__ __launch_bounds__(256) void k_wcvt1(const float* __restrict__ w,
        unsigned short* __restrict__ o) {
    int i = blockIdx.x*256 + threadIdx.x;        // 131072
    int rt = i >> 13, rem = i & 8191;
    int co = rem >> 6, ci = rem & 63;
    o[i] = f2bf(w[((size_t)rt*64 + ci)*128 + co]);
}

// ---------------- convT1 (bf16 MFMA): zqb[65536,64] -> g1b bf16, GELU
// Block (b,qq,ey,par): M=128 px (2 half-rows of 64), N=128 co, K=4 taps x 64 ci.
__global__ __launch_bounds__(256) void k_convt1m(const unsigned short* __restrict__ zqb,
        const unsigned short* __restrict__ w1b, const float* __restrict__ bias,
        unsigned short* __restrict__ out) {
    __shared__ __align__(16) unsigned short A[2*128*32];
    __shared__ __align__(16) unsigned short Bm[2*128*32];
    const int tid = threadIdx.x;
    const int par = blockIdx.x & 1;
    const int ey  = (blockIdx.x >> 1) & 1;
    const int qq  = (blockIdx.x >> 2) & 31;
    const int b   = blockIdx.x >> 7;
    const int q0  = qq*2;
    const int lane = tid & 63, l15 = lane & 15, q = lane >> 4;
    const int wid = tid >> 6, wm = wid >> 1, wn = wid & 1;

    f32x4 acc[4][4];
    #pragma unroll
    for (int fm = 0; fm < 4; ++fm)
        #pragma unroll
        for (int fn = 0; fn < 4; ++fn) acc[fm][fn] = (f32x4){0.f,0.f,0.f,0.f};

    for (int tap = 0; tap < 4; ++tap) {
        int rr = tap >> 1, tt = tap & 1;
        int r = ey + 2*rr, t = par + 2*tt;
        int rt = r*4 + t;
        __syncthreads();
        for (int i = tid; i < 1024; i += 256) {
            int px = i >> 3, cc = i & 7, ci0 = cc*8;
            int qv = q0 + (px >> 6), p = px & 63;
            int iy = qv + ey - 1 + rr, ix = p + par - 1 + tt;
            uint4 v = make_uint4(0,0,0,0);
            if ((unsigned)iy < 64u && (unsigned)ix < 64u)
                v = *(const uint4*)(zqb + (((size_t)(b*64) + iy)*64 + ix)*64 + ci0);
            *(uint4*)&A[((cc>>2)*128 + px)*32 + (ci0 & 31)] = v;
        }
        for (int i = tid; i < 1024; i += 256) {
            int co = i >> 3, cc = i & 7, ci0 = cc*8;
            uint4 v = *(const uint4*)(w1b + ((size_t)rt*128 + co)*64 + ci0);
            *(uint4*)&Bm[((cc>>2)*128 + co)*32 + (ci0 & 31)] = v;
        }
        __syncthreads();
        #pragma unroll
        for (int kc = 0; kc < 2; ++kc) {
            short8 af[4], bf[4];
            #pragma unroll
            for (int fm = 0; fm < 4; ++fm)
                af[fm] = *(const short8*)&A[(kc*128 + wm*64 + fm*16 + l15)*32 + q*8];
            #pragma unroll
            for (int fn = 0; fn < 4; ++fn)
                bf[fn] = *(const short8*)&Bm[(kc*128 + wn*64 + fn*16 + l15)*32 + q*8];
            #pragma unroll
            for (int fm = 0; fm < 4; ++fm)
                #pragma unroll
                for (int fn = 0; fn < 4; ++fn)
                    acc[fm][fn] = __builtin_amdgcn_mfma_f32_16x16x32_bf16(
                        af[fm], bf[fn], acc[fm][fn], 0, 0, 0);
        }
    }
    float bv[4];
    #pragma unroll
    for (int fn = 0; fn < 4; ++fn) bv[fn] = bias[wn*64 + fn*16 + l15];
    #pragma unroll
    for (int fm = 0; fm < 4; ++fm)
        #pragma unroll
        for (int rg = 0; rg < 4; ++rg) {
            int px = wm*64 + fm*16 + q*4 + rg;
            int qv = q0 + (px >> 6), p = px & 63;
            int oy = 2*qv + ey, ox = par + 2*p;
            unsigned short* o = out + (((size_t)(b*128) + oy)*128 + ox)*128;
            #pragma unroll
            for (int fn = 0; fn < 4; ++fn)
                o[wn*64 + fn*16 + l15] = f2bf(gelu_f(acc[fm][fn][rg] + bv[fn]));
        }
}

// ---------------- convT2 (bf16 MFMA) + fused final 1x1: g1b -> x_rec
__global__ __launch_bounds__(256) void k_convt2(const unsigned short* __restrict__ g1b,
        const unsigned short* __restrict__ wtb, const float* __restrict__ b2,
        const float* __restrict__ w3, const float* __restrict__ b3,
        float* __restrict__ xrec) {
    union SM {
        struct { unsigned short A[4*128*32]; unsigned short B[4*128*32]; } s; // 64 KB
        float red[128*32*3];                                                  // 48 KB
    };
    __shared__ __align__(16) union SM sm;
    const int tid  = threadIdx.x;
    const int par  = blockIdx.x & 1;
    const int oy   = (blockIdx.x >> 1) & 255;
    const int b    = blockIdx.x >> 9;
    const int lane = tid & 63, l15 = lane & 15, q = lane >> 4;
    const int wid  = tid >> 6, wm = wid >> 1, wn = wid & 1;
    const int ey = oy & 1, qy = oy >> 1;

    f32x4 acc[4][4];
    #pragma unroll
    for (int fm = 0; fm < 4; ++fm)
        #pragma unroll
        for (int fn = 0; fn < 4; ++fn) acc[fm][fn] = (f32x4){0.f,0.f,0.f,0.f};

    for (int tap = 0; tap < 4; ++tap) {
        int rr = tap >> 1, tt = tap & 1;
        int r = ey + rr*2, t = par + tt*2;
        int iy = qy + ey - 1 + rr;
        bool yok = (unsigned)iy < 128u;
        const unsigned short* arow = g1b + ((size_t)(b*128) + (yok?iy:0))*128*128;
        const unsigned short* brow = wtb + (size_t)(r*4 + t)*16384;
        __syncthreads();
        for (int i = tid; i < 2048; i += 256) {
            int px = i >> 4, cc = i & 15;
            int ci0 = cc*8;
            int ix = px + par - 1 + tt;
            uint4 v = make_uint4(0,0,0,0);
            if (yok && (unsigned)ix < 128u)
                v = *(const uint4*)(arow + (size_t)ix*128 + ci0);
            *(uint4*)&sm.s.A[((cc>>2)*128 + px)*32 + (ci0 & 31)] = v;
        }
        for (int i = tid; i < 2048; i += 256) {
            int co = i >> 4, cc = i & 15;
            int ci0 = cc*8;
            uint4 v = *(const uint4*)(brow + (size_t)co*128 + ci0);
            *(uint4*)&sm.s.B[((cc>>2)*128 + co)*32 + (ci0 & 31)] = v;
        }
        __syncthreads();
        #pragma unroll
        for (int kc = 0; kc < 4; ++kc) {
            short8 af[4], bf[4];
            #pragma unroll
            for (int fm = 0; fm < 4; ++fm)
                af[fm] = *(const short8*)&sm.s.A[((kc*128 + wm*64 + fm*16 + l15)*32) + q*8];
            #pragma unroll
            for (int fn = 0; fn < 4; ++fn)
                bf[fn] = *(const short8*)&sm.s.B[((kc*128 + wn*64 + fn*16 + l15)*32) + q*8];
            #pragma unroll
            for (int fm = 0; fm < 4; ++fm)
                #pragma unroll
                for (int fn = 0; fn < 4; ++fn)
                    acc[fm][fn] = __builtin_amdgcn_mfma_f32_16x16x32_bf16(
                        af[fm], bf[fn], acc[fm][fn], 0, 0, 0);
        }
    }

    float b2v[4];
    float w3v[4][3];
    #pragma unroll
    for (int fn = 0; fn < 4; ++fn) {
        int co = wn*64 + fn*16 + l15;
        b2v[fn] = b2[co];
        w3v[fn][0] = w3[co*3+0]; w3v[fn][1] = w3[co*3+1]; w3v[fn][2] = w3[co*3+2];
    }
    __syncthreads();
    #pragma unroll
    for (int fm = 0; fm < 4; ++fm) {
        #pragma unroll
        for (int rg = 0; rg < 4; ++rg) {
            int px = wm*64 + fm*16 + q*4 + rg;
            float s0 = 0.f, s1 = 0.f, s2 = 0.f;
            #pragma unroll
            for (int fn = 0; fn < 4; ++fn) {
                float y = gelu_f(acc[fm][fn][rg] + b2v[fn]);
                s0 += y*w3v[fn][0]; s1 += y*w3v[fn][1]; s2 += y*w3v[fn][2];
            }
            int slot = wn*16 + l15;
            sm.red[(px*32 + slot)*3 + 0] = s0;
            sm.red[(px*32 + slot)*3 + 1] = s1;
            sm.red[(px*32 + slot)*3 + 2] = s2;
        }
    }
    __syncthreads();
    for (int o = tid; o < 384; o += 256) {
        int px = o/3, jj = o - px*3;
        float s = b3[jj];
        #pragma unroll
        for (int g = 0; g < 32; ++g) s += sm.red[(px*32 + g)*3 + jj];
        xrec[(((size_t)(b*256) + oy)*256 + (par + 2*px))*3 + jj] = s;
    }
}

__global__ void k_zero(float* p) { if (threadIdx.x == 0) p[0] = 0.f; }

__global__ void k_finalize(const float* __restrict__ loss_acc, float* __restrict__ o) {
    if (threadIdx.x == 0) {
        float v = loss_acc[0] * (1.0f/4194304.0f);
        o[0] = v;
        o[1] = v;
    }
}

extern "C" void kernel_launch(void* const* d_in, const int* in_sizes, int n_in,
                              void* d_out, int out_size, void* d_ws, size_t ws_size,
                              hipStream_t stream) {
    (void)in_sizes; (void)n_in; (void)out_size; (void)ws_size;
    const float* x   = (const float*)d_in[0];
    const float* ew1 = (const float*)d_in[1];
    const float* eb1 = (const float*)d_in[2];
    const float* ew2 = (const float*)d_in[3];
    const float* eb2 = (const float*)d_in[4];
    const float* ew3 = (const float*)d_in[5];
    const float* eb3 = (const float*)d_in[6];
    const float* cb  = (const float*)d_in[7];
    const float* dw1 = (const float*)d_in[8];
    const float* db1 = (const float*)d_in[9];
    const float* dw2 = (const float*)d_in[10];
    const float* db2 = (const float*)d_in[11];
    const float* dw3 = (const float*)d_in[12];
    const float* db3 = (const float*)d_in[13];

    float* ws = (float*)d_ws;
    unsigned short* h1h  = (unsigned short*)(ws);                 // 33,554,432 us (16.78M f)
    unsigned short* h1l  = (unsigned short*)(ws + 16777216);      // 33,554,432 us
    float*          h2   = ws + 33554432;                         //  8,388,608 f
    float*          ze   = ws + 41943040;                         //  4,194,304 f
    unsigned short* zqb  = (unsigned short*)(ws + 46137344);      //  4,194,304 us
    unsigned short* we2h = (unsigned short*)(ws + 48234496);      //    262,144 us
    unsigned short* we2l = (unsigned short*)(ws + 48365568);      //    262,144 us
    unsigned short* wd2b = (unsigned short*)(ws + 48496640);      //    262,144 us
    unsigned short* wd1b = (unsigned short*)(ws + 48627712);      //    131,072 us
    float*          lacc = ws + 48693248;                         //          1 f
    unsigned short* g1b  = h1h;   // reuse (dead after conv2m)

    float* xrec = (float*)d_out;            // 3,145,728 f
    float* tokf = xrec + 3145728;           //    65,536 f
    float* loss = tokf + 65536;             //         2 f

    k_wsplit2 <<<1024, 256, 0, stream>>>(ew2, we2h, we2l);
    k_wcvt2   <<<1024, 256, 0, stream>>>(dw2, wd2b);
    k_wcvt1   <<< 512, 256, 0, stream>>>(dw1, wd1b);
    k_conv1   <<<4096, 256, 0, stream>>>(x, ew1, eb1, h1h, h1l);
    k_conv2m  <<< 512, 256, 0, stream>>>(h1h, h1l, we2h, we2l, eb2, h2);
    k_conv3   <<< 512, 256, 0, stream>>>(h2, ew3, eb3, ze);
    k_zero    <<<   1,  64, 0, stream>>>(lacc);
    k_vq      <<<1024, 256, 0, stream>>>(ze, cb, zqb, tokf, lacc);
    k_convt1m <<<4096, 256, 0, stream>>>(zqb, wd1b, db1, g1b);
    k_convt2  <<<8192, 256, 0, stream>>>(g1b, wd2b, db2, dw3, db3, xrec);
    k_finalize<<<   1,  64, 0, stream>>>(lacc, loss);
}

// Round 5
// 867.669 us; speedup vs baseline: 3.4241x; 1.1512x over previous
//
#include <hip/hip_runtime.h>
#include <math.h>

// Shapes: B=16, x[16,256,256,3], h1[16,128,128,128], h2[16,64,64,128],
// z_e/z_q[65536,64], g1[16,128,128,128](bf16), x_rec[16,256,256,3], K=1024.
//
// R5: convt2 restructured: raw-A staged once per ci-chunk (taps share it via
// shifted ds_reads), global_load_lds width-16 staging (no VGPR roundtrip, no
// staging-write bank conflicts), LDS 64->49.4 KB (2->3 blocks/CU).

typedef __attribute__((ext_vector_type(8))) short short8;
typedef __attribute__((ext_vector_type(4))) float f32x4;

__device__ __forceinline__ float gelu_f(float x) {
    float x3 = x*x*x;
    return 0.5f*x*(1.0f + tanhf(0.7978845608028654f*(x + 0.044715f*x3)));
}

__device__ __forceinline__ unsigned short f2bf(float f) {
    unsigned int u = __float_as_uint(f);
    u = (u + 0x7FFFu + ((u >> 16) & 1u)) >> 16;   // RNE
    return (unsigned short)u;
}
__device__ __forceinline__ float bf2f(unsigned short h) {
    return __uint_as_float(((unsigned int)h) << 16);
}

typedef const __attribute__((address_space(1))) unsigned int* gp_t;
typedef __attribute__((address_space(3))) unsigned int* lp_t;
__device__ __forceinline__ void async16(const void* g, void* l) {
    __builtin_amdgcn_global_load_lds((gp_t)g, (lp_t)l, 16, 0, 0);
}

// ---------------- conv1: x[16,256,256,3] -> h1 hi/lo bf16 planes, 4x4 s2 SAME, GELU
__global__ __launch_bounds__(256) void k_conv1(const float* __restrict__ x,
        const float* __restrict__ w, const float* __restrict__ bias,
        unsigned short* __restrict__ outh, unsigned short* __restrict__ outl) {
    __shared__ __align__(16) float ws[48*128];
    __shared__ __align__(16) float xs[4][390];
    const int tid = threadIdx.x;
    const int blk = blockIdx.x;
    const int oxt = blk & 1;
    const int oy  = (blk >> 1) & 127;
    const int b   = blk >> 8;
    const int cg = tid & 15, pg = tid >> 4;
    const int c0a = cg*4, c0b = 64 + cg*4;
    const int p0 = pg*4;
    const int ox0 = oxt*64;

    for (int i = tid; i < 6144; i += 256) ws[i] = w[i];
    for (int r = 0; r < 4; ++r) {
        int iy = 2*oy + r - 1;
        bool yok = (unsigned)iy < 256u;
        const float* xrow = x + ((size_t)(b*256) + iy)*256*3;
        for (int i = tid; i < 390; i += 256) {
            int ixl = i/3, ci = i - ixl*3;
            int ix = 2*ox0 - 1 + ixl;
            xs[r][i] = (yok && (unsigned)ix < 256u) ? xrow[(size_t)ix*3 + ci] : 0.f;
        }
    }
    __syncthreads();

    float acc[4][8];
    #pragma unroll
    for (int j = 0; j < 4; ++j)
        #pragma unroll
        for (int i = 0; i < 8; ++i) acc[j][i] = 0.f;

    #pragma unroll 6
    for (int pos = 0; pos < 48; ++pos) {
        int r = pos/12, tc = pos - r*12;
        int t = tc/3,  ci = tc - t*3;
        float4 w0 = *(const float4*)&ws[pos*128 + c0a];
        float4 w1 = *(const float4*)&ws[pos*128 + c0b];
        #pragma unroll
        for (int j = 0; j < 4; ++j) {
            float av = xs[r][(2*(p0+j) + t)*3 + ci];
            acc[j][0] += av*w0.x; acc[j][1] += av*w0.y;
            acc[j][2] += av*w0.z; acc[j][3] += av*w0.w;
            acc[j][4] += av*w1.x; acc[j][5] += av*w1.y;
            acc[j][6] += av*w1.z; acc[j][7] += av*w1.w;
        }
    }
    float bv[8];
    #pragma unroll
    for (int i = 0; i < 4; ++i) { bv[i] = bias[c0a+i]; bv[4+i] = bias[c0b+i]; }
    #pragma unroll
    for (int j = 0; j < 4; ++j) {
        int ox = ox0 + p0 + j;
        size_t base = (((size_t)(b*128) + oy)*128 + ox)*128;
        ushort4 ha, hb, la, lb;
        float y;
        y = gelu_f(acc[j][0]+bv[0]); ha.x = f2bf(y); la.x = f2bf(y - bf2f(ha.x));
        y = gelu_f(acc[j][1]+bv[1]); ha.y = f2bf(y); la.y = f2bf(y - bf2f(ha.y));
        y = gelu_f(acc[j][2]+bv[2]); ha.z = f2bf(y); la.z = f2bf(y - bf2f(ha.z));
        y = gelu_f(acc[j][3]+bv[3]); ha.w = f2bf(y); la.w = f2bf(y - bf2f(ha.w));
        y = gelu_f(acc[j][4]+bv[4]); hb.x = f2bf(y); lb.x = f2bf(y - bf2f(hb.x));
        y = gelu_f(acc[j][5]+bv[5]); hb.y = f2bf(y); lb.y = f2bf(y - bf2f(hb.y));
        y = gelu_f(acc[j][6]+bv[6]); hb.z = f2bf(y); lb.z = f2bf(y - bf2f(hb.z));
        y = gelu_f(acc[j][7]+bv[7]); hb.w = f2bf(y); lb.w = f2bf(y - bf2f(hb.w));
        *(ushort4*)&outh[base + c0a] = ha;
        *(ushort4*)&outh[base + c0b] = hb;
        *(ushort4*)&outl[base + c0a] = la;
        *(ushort4*)&outl[base + c0b] = lb;
    }
}

// ---------------- conv2 (split-bf16 MFMA): h1 hi/lo -> h2[16,64,64,128] f32, GELU
__global__ __launch_bounds__(256) void k_conv2m(const unsigned short* __restrict__ h1h,
        const unsigned short* __restrict__ h1l,
        const unsigned short* __restrict__ w2h, const unsigned short* __restrict__ w2l,
        const float* __restrict__ bias, float* __restrict__ out) {
    __shared__ __align__(16) unsigned short Ah[2*128*32];
    __shared__ __align__(16) unsigned short Al[2*128*32];
    __shared__ __align__(16) unsigned short Bh[2*128*32];
    __shared__ __align__(16) unsigned short Bl[2*128*32];
    const int tid = threadIdx.x;
    const int yy = blockIdx.x & 31;
    const int b  = blockIdx.x >> 5;
    const int oy0 = yy*2;
    const int lane = tid & 63, l15 = lane & 15, q = lane >> 4;
    const int wid = tid >> 6, wm = wid >> 1, wn = wid & 1;

    f32x4 acc[4][4];
    #pragma unroll
    for (int fm = 0; fm < 4; ++fm)
        #pragma unroll
        for (int fn = 0; fn < 4; ++fn) acc[fm][fn] = (f32x4){0.f,0.f,0.f,0.f};

    for (int tap = 0; tap < 16; ++tap) {
        int r = tap >> 2, t = tap & 3;
        for (int cs = 0; cs < 2; ++cs) {
            __syncthreads();
            for (int i = tid; i < 1024; i += 256) {
                int px = i >> 3, cc = i & 7, ci0 = cc*8;
                int oy = oy0 + (px >> 6), ox = px & 63;
                int iy = 2*oy + r - 1, ix = 2*ox + t - 1;
                uint4 vh = make_uint4(0,0,0,0), vl = make_uint4(0,0,0,0);
                if ((unsigned)iy < 128u && (unsigned)ix < 128u) {
                    size_t off = (((size_t)(b*128) + iy)*128 + ix)*128 + cs*64 + ci0;
                    vh = *(const uint4*)(h1h + off);
                    vl = *(const uint4*)(h1l + off);
                }
                int idx = ((cc>>2)*128 + px)*32 + (ci0 & 31);
                *(uint4*)&Ah[idx] = vh;
                *(uint4*)&Al[idx] = vl;
            }
            for (int i = tid; i < 1024; i += 256) {
                int co = i >> 3, cc = i & 7, ci0 = cc*8;
                size_t off = ((size_t)tap*128 + co)*128 + cs*64 + ci0;
                uint4 vh = *(const uint4*)(w2h + off);
                uint4 vl = *(const uint4*)(w2l + off);
                int idx = ((cc>>2)*128 + co)*32 + (ci0 & 31);
                *(uint4*)&Bh[idx] = vh;
                *(uint4*)&Bl[idx] = vl;
            }
            __syncthreads();
            #pragma unroll
            for (int kc = 0; kc < 2; ++kc) {
                short8 ah[4], al[4], bh[4], bl[4];
                #pragma unroll
                for (int fm = 0; fm < 4; ++fm) {
                    int row = (kc*128 + wm*64 + fm*16 + l15)*32 + q*8;
                    ah[fm] = *(const short8*)&Ah[row];
                    al[fm] = *(const short8*)&Al[row];
                }
                #pragma unroll
                for (int fn = 0; fn < 4; ++fn) {
                    int row = (kc*128 + wn*64 + fn*16 + l15)*32 + q*8;
                    bh[fn] = *(const short8*)&Bh[row];
                    bl[fn] = *(const short8*)&Bl[row];
                }
                #pragma unroll
                for (int fm = 0; fm < 4; ++fm)
                    #pragma unroll
                    for (int fn = 0; fn < 4; ++fn) {
                        acc[fm][fn] = __builtin_amdgcn_mfma_f32_16x16x32_bf16(
                            ah[fm], bh[fn], acc[fm][fn], 0, 0, 0);
                        acc[fm][fn] = __builtin_amdgcn_mfma_f32_16x16x32_bf16(
                            al[fm], bh[fn], acc[fm][fn], 0, 0, 0);
                        acc[fm][fn] = __builtin_amdgcn_mfma_f32_16x16x32_bf16(
                            ah[fm], bl[fn], acc[fm][fn], 0, 0, 0);
                    }
            }
        }
    }
    float bv[4];
    #pragma unroll
    for (int fn = 0; fn < 4; ++fn) bv[fn] = bias[wn*64 + fn*16 + l15];
    #pragma unroll
    for (int fm = 0; fm < 4; ++fm)
        #pragma unroll
        for (int rg = 0; rg < 4; ++rg) {
            int px = wm*64 + fm*16 + q*4 + rg;
            int oy = oy0 + (px >> 6), ox = px & 63;
            float* o = out + (((size_t)(b*64) + oy)*64 + ox)*128;
            #pragma unroll
            for (int fn = 0; fn < 4; ++fn)
                o[wn*64 + fn*16 + l15] = gelu_f(acc[fm][fn][rg] + bv[fn]);
        }
}

// ---------------- conv3 (1x1, 128->64, f32): h2 -> z_e [65536,64]
__global__ __launch_bounds__(256) void k_conv3(const float* __restrict__ in,
        const float* __restrict__ w, const float* __restrict__ bias,
        float* __restrict__ out) {
    __shared__ __align__(16) float xs[128*33];
    __shared__ __align__(16) float wb[32*64];
    const int tid = threadIdx.x;
    const size_t pix0 = (size_t)blockIdx.x * 128;
    const int cg = tid & 7, pg = tid >> 3;
    const int c0a = cg*4, c0b = 32 + cg*4;
    const int p0 = pg*4;

    float acc[4][8];
    #pragma unroll
    for (int j = 0; j < 4; ++j)
        #pragma unroll
        for (int i = 0; i < 8; ++i) acc[j][i] = 0.f;

    for (int cs = 0; cs < 4; ++cs) {
        __syncthreads();
        for (int i = tid; i < 4096; i += 256) {
            int p = i >> 5, ci = i & 31;
            xs[p*33 + ci] = in[(pix0 + p)*128 + cs*32 + ci];
        }
        for (int i = tid; i < 2048; i += 256) {
            int ci = i >> 6, c = i & 63;
            wb[i] = w[(size_t)(cs*32 + ci)*64 + c];
        }
        __syncthreads();
        #pragma unroll 8
        for (int ci = 0; ci < 32; ++ci) {
            float a_[4];
            #pragma unroll
            for (int j = 0; j < 4; ++j) a_[j] = xs[(p0+j)*33 + ci];
            float4 b0 = *(const float4*)&wb[ci*64 + c0a];
            float4 b1 = *(const float4*)&wb[ci*64 + c0b];
            #pragma unroll
            for (int j = 0; j < 4; ++j) {
                acc[j][0] += a_[j]*b0.x; acc[j][1] += a_[j]*b0.y;
                acc[j][2] += a_[j]*b0.z; acc[j][3] += a_[j]*b0.w;
                acc[j][4] += a_[j]*b1.x; acc[j][5] += a_[j]*b1.y;
                acc[j][6] += a_[j]*b1.z; acc[j][7] += a_[j]*b1.w;
            }
        }
    }
    #pragma unroll
    for (int j = 0; j < 4; ++j) {
        float* o = out + (pix0 + p0 + j)*64;
        float4 va, vb;
        va.x = acc[j][0]+bias[c0a+0]; va.y = acc[j][1]+bias[c0a+1];
        va.z = acc[j][2]+bias[c0a+2]; va.w = acc[j][3]+bias[c0a+3];
        vb.x = acc[j][4]+bias[c0b+0]; vb.y = acc[j][5]+bias[c0b+1];
        vb.z = acc[j][6]+bias[c0b+2]; vb.w = acc[j][7]+bias[c0b+3];
        *(float4*)&o[c0a] = va;
        *(float4*)&o[c0b] = vb;
    }
}

// ---------------- VQ: f32 (exact), writes z_q as bf16 for the decoder
__global__ __launch_bounds__(256) void k_vq(const float* __restrict__ ze,
        const float* __restrict__ cb, unsigned short* __restrict__ zqb,
        float* __restrict__ tok, float* __restrict__ loss_acc) {
    __shared__ __align__(16) float zs[64*65];
    __shared__ __align__(16) float bt[64*132];
    __shared__ float es[128];
    __shared__ float z2s[64];
    __shared__ float rmin[64*16];
    __shared__ int   ridx[64*16];
    __shared__ int   widx[64];
    __shared__ float wsum[4];
    const int tid = threadIdx.x;
    const size_t tok0 = (size_t)blockIdx.x * 64;
    const int cg = tid & 15, pg = tid >> 4;
    const int k0a = cg*4, k0b = 64 + cg*4;
    const int t0 = pg*4;

    for (int i = tid; i < 4096; i += 256) {
        int tk = i >> 6, d = i & 63;
        zs[tk*65 + d] = ze[(tok0 + tk)*64 + d];
    }
    __syncthreads();
    if (tid < 64) {
        float s = 0.f;
        for (int d = 0; d < 64; ++d) { float v = zs[tid*65 + d]; s += v*v; }
        z2s[tid] = s;
    }

    float bmin[4] = {3.4e38f,3.4e38f,3.4e38f,3.4e38f};
    int   bidx[4] = {0,0,0,0};

    for (int ch = 0; ch < 8; ++ch) {
        __syncthreads();
        for (int i = tid; i < 8192; i += 256) {
            int k = i >> 6, d = i & 63;
            bt[d*132 + k] = cb[((size_t)(ch*128) + k)*64 + d];
        }
        __syncthreads();
        if (tid < 128) {
            float s = 0.f;
            for (int d = 0; d < 64; ++d) { float v = bt[d*132 + tid]; s += v*v; }
            es[tid] = s;
        }
        __syncthreads();
        float acc[4][8];
        #pragma unroll
        for (int j = 0; j < 4; ++j)
            #pragma unroll
            for (int i = 0; i < 8; ++i) acc[j][i] = 0.f;
        #pragma unroll 4
        for (int d = 0; d < 64; ++d) {
            float a_[4];
            #pragma unroll
            for (int j = 0; j < 4; ++j) a_[j] = zs[(t0+j)*65 + d];
            float4 b0 = *(const float4*)&bt[d*132 + k0a];
            float4 b1 = *(const float4*)&bt[d*132 + k0b];
            #pragma unroll
            for (int j = 0; j < 4; ++j) {
                acc[j][0] += a_[j]*b0.x; acc[j][1] += a_[j]*b0.y;
                acc[j][2] += a_[j]*b0.z; acc[j][3] += a_[j]*b0.w;
                acc[j][4] += a_[j]*b1.x; acc[j][5] += a_[j]*b1.y;
                acc[j][6] += a_[j]*b1.z; acc[j][7] += a_[j]*b1.w;
            }
        }
        #pragma unroll
        for (int j = 0; j < 4; ++j) {
            float z2 = z2s[t0+j];
            #pragma unroll
            for (int i = 0; i < 4; ++i) {
                float dist = (z2 + es[k0a+i]) - 2.f*acc[j][i];
                int idx = ch*128 + k0a + i;
                if (dist < bmin[j]) { bmin[j] = dist; bidx[j] = idx; }
            }
            #pragma unroll
            for (int i = 0; i < 4; ++i) {
                float dist = (z2 + es[k0b+i]) - 2.f*acc[j][4+i];
                int idx = ch*128 + k0b + i;
                if (dist < bmin[j]) { bmin[j] = dist; bidx[j] = idx; }
            }
        }
    }
    #pragma unroll
    for (int j = 0; j < 4; ++j) {
        rmin[(t0+j)*16 + cg] = bmin[j];
        ridx[(t0+j)*16 + cg] = bidx[j];
    }
    __syncthreads();
    if (tid < 64) {
        float bv = rmin[tid*16]; int bi = ridx[tid*16];
        for (int g = 1; g < 16; ++g) {
            float v = rmin[tid*16 + g]; int ii = ridx[tid*16 + g];
            if (v < bv || (v == bv && ii < bi)) { bv = v; bi = ii; }
        }
        widx[tid] = bi;
        tok[tok0 + tid] = (float)bi;
    }
    __syncthreads();
    float lsum = 0.f;
    for (int i = tid; i < 4096; i += 256) {
        int tk = i >> 6, d = i & 63;
        float v = cb[(size_t)widx[tk]*64 + d];
        zqb[(tok0 + tk)*64 + d] = f2bf(v);
        float diff = v - zs[tk*65 + d];
        lsum += diff*diff;
    }
    #pragma unroll
    for (int off = 32; off > 0; off >>= 1) lsum += __shfl_down(lsum, off, 64);
    if ((tid & 63) == 0) wsum[tid >> 6] = lsum;
    __syncthreads();
    if (tid == 0) atomicAdd(loss_acc, wsum[0]+wsum[1]+wsum[2]+wsum[3]);
}

// ---------------- weight prep kernels
__global__ __launch_bounds__(256) void k_wsplit2(const float* __restrict__ w,
        unsigned short* __restrict__ hi, unsigned short* __restrict__ lo) {
    int i = blockIdx.x*256 + threadIdx.x;        // 262144
    int rt = i >> 14, rem = i & 16383;
    int co = rem >> 7, ci = rem & 127;
    float v = w[((size_t)rt*128 + ci)*128 + co];
    unsigned short h = f2bf(v);
    hi[i] = h;
    lo[i] = f2bf(v - bf2f(h));
}
__global__ __launch_bounds__(256) void k_wcvt2(const float* __restrict__ w,
        unsigned short* __restrict__ o) {
    int i = blockIdx.x*256 + threadIdx.x;        // 262144
    int rt = i >> 14, rem = i & 16383;
    int co = rem >> 7, ci = rem & 127;
    o[i] = f2bf(w[((size_t)rt*128 + ci)*128 + co]);
}
__global__ __launch_bounds__(256) void k_wcvt1(const float* __restrict__ w,
        unsigned short* __restrict__ o) {
    int i = blockIdx.x*256 + threadIdx.x;        // 131072
    int rt = i >> 13, rem = i & 8191;
    int co = rem >> 6, ci = rem & 63;
    o[i] = f2bf(w[((size_t)rt*64 + ci)*128 + co]);
}

// ---------------- convT1 (bf16 MFMA): zqb[65536,64] -> g1b bf16, GELU
__global__ __launch_bounds__(256) void k_convt1m(const unsigned short* __restrict__ zqb,
        const unsigned short* __restrict__ w1b, const float* __restrict__ bias,
        unsigned short* __restrict__ out) {
    __shared__ __align__(16) unsigned short A[2*128*32];
    __shared__ __align__(16) unsigned short Bm[2*128*32];
    const int tid = threadIdx.x;
    const int par = blockIdx.x & 1;
    const int ey  = (blockIdx.x >> 1) & 1;
    const int qq  = (blockIdx.x >> 2) & 31;
    const int b   = blockIdx.x >> 7;
    const int q0  = qq*2;
    const int lane = tid & 63, l15 = lane & 15, q = lane >> 4;
    const int wid = tid >> 6, wm = wid >> 1, wn = wid & 1;

    f32x4 acc[4][4];
    #pragma unroll
    for (int fm = 0; fm < 4; ++fm)
        #pragma unroll
        for (int fn = 0; fn < 4; ++fn) acc[fm][fn] = (f32x4){0.f,0.f,0.f,0.f};

    for (int tap = 0; tap < 4; ++tap) {
        int rr = tap >> 1, tt = tap & 1;
        int r = ey + 2*rr, t = par + 2*tt;
        int rt = r*4 + t;
        __syncthreads();
        for (int i = tid; i < 1024; i += 256) {
            int px = i >> 3, cc = i & 7, ci0 = cc*8;
            int qv = q0 + (px >> 6), p = px & 63;
            int iy = qv + ey - 1 + rr, ix = p + par - 1 + tt;
            uint4 v = make_uint4(0,0,0,0);
            if ((unsigned)iy < 64u && (unsigned)ix < 64u)
                v = *(const uint4*)(zqb + (((size_t)(b*64) + iy)*64 + ix)*64 + ci0);
            *(uint4*)&A[((cc>>2)*128 + px)*32 + (ci0 & 31)] = v;
        }
        for (int i = tid; i < 1024; i += 256) {
            int co = i >> 3, cc = i & 7, ci0 = cc*8;
            uint4 v = *(const uint4*)(w1b + ((size_t)rt*128 + co)*64 + ci0);
            *(uint4*)&Bm[((cc>>2)*128 + co)*32 + (ci0 & 31)] = v;
        }
        __syncthreads();
        #pragma unroll
        for (int kc = 0; kc < 2; ++kc) {
            short8 af[4], bf[4];
            #pragma unroll
            for (int fm = 0; fm < 4; ++fm)
                af[fm] = *(const short8*)&A[(kc*128 + wm*64 + fm*16 + l15)*32 + q*8];
            #pragma unroll
            for (int fn = 0; fn < 4; ++fn)
                bf[fn] = *(const short8*)&Bm[(kc*128 + wn*64 + fn*16 + l15)*32 + q*8];
            #pragma unroll
            for (int fm = 0; fm < 4; ++fm)
                #pragma unroll
                for (int fn = 0; fn < 4; ++fn)
                    acc[fm][fn] = __builtin_amdgcn_mfma_f32_16x16x32_bf16(
                        af[fm], bf[fn], acc[fm][fn], 0, 0, 0);
        }
    }
    float bv[4];
    #pragma unroll
    for (int fn = 0; fn < 4; ++fn) bv[fn] = bias[wn*64 + fn*16 + l15];
    #pragma unroll
    for (int fm = 0; fm < 4; ++fm)
        #pragma unroll
        for (int rg = 0; rg < 4; ++rg) {
            int px = wm*64 + fm*16 + q*4 + rg;
            int qv = q0 + (px >> 6), p = px & 63;
            int oy = 2*qv + ey, ox = par + 2*p;
            unsigned short* o = out + (((size_t)(b*128) + oy)*128 + ox)*128;
            #pragma unroll
            for (int fn = 0; fn < 4; ++fn)
                o[wn*64 + fn*16 + l15] = f2bf(gelu_f(acc[fm][fn][rg] + bv[fn]));
        }
}

// ---------------- convT2 (bf16 MFMA, raw-A shared across taps, async staging)
// Block (b,oy,par): M=128 px, N=128 co, K=4 taps x 128 ci (chunked by 32 ci).
// LDS: Araw[2 rows][130 cols(+halo)][32 ci] + B4[4 taps][128 co][32 ci].
__global__ __launch_bounds__(256) void k_convt2(const unsigned short* __restrict__ g1b,
        const unsigned short* __restrict__ wtb, const float* __restrict__ b2,
        const float* __restrict__ w3, const float* __restrict__ b3,
        const float* __restrict__ zsc, float* __restrict__ xrec) {
    union SM {
        struct {
            unsigned short Araw[2*130*32];   // 16640 B
            unsigned short B4[4*128*32];     // 32768 B
        } s;
        float red[128*32*3];                 // 49152 B
    };
    __shared__ __align__(16) union SM sm;
    const int tid  = threadIdx.x;
    const int par  = blockIdx.x & 1;
    const int oy   = (blockIdx.x >> 1) & 255;
    const int b    = blockIdx.x >> 9;
    const int lane = tid & 63, l15 = lane & 15, q = lane >> 4;
    const int wid  = tid >> 6, wm = wid >> 1, wn = wid & 1;
    const int ey = oy & 1, qy = oy >> 1;
    const int iy0 = qy + ey - 1;

    f32x4 acc[4][4];
    #pragma unroll
    for (int fm = 0; fm < 4; ++fm)
        #pragma unroll
        for (int fn = 0; fn < 4; ++fn) acc[fm][fn] = (f32x4){0.f,0.f,0.f,0.f};

    // zero halo columns (raw cols -1 and 128 -> lds cols 0 and 129); they are
    // always out of range, and bulk staging never touches them.
    if (tid < 16) {
        int rr = tid >> 3, side = (tid >> 2) & 1, qtr = tid & 3;
        int col = side ? 129 : 0;
        *(uint4*)&sm.s.Araw[(rr*130 + col)*32 + qtr*8] = make_uint4(0,0,0,0);
    }

    // precompute tap rt indices (wave-uniform)
    int rt_tab[4];
    #pragma unroll
    for (int tap = 0; tap < 4; ++tap) {
        int rr = tap >> 1, tt = tap & 1;
        rt_tab[tap] = (ey + 2*rr)*4 + (par + 2*tt);
    }

    for (int kc = 0; kc < 4; ++kc) {
        __syncthreads();   // protect prior chunk's reads (and halo zeros, 1st iter)
        // A raw: 2 rows x 128 cols x 32 ci = 16 segments of 1KB; 4 per wave.
        #pragma unroll
        for (int j = 0; j < 4; ++j) {
            int seg = wid*4 + j;              // 0..15
            int rr = seg >> 3, s = seg & 7;   // row, col-block
            int px = s*16 + (lane >> 2);
            int ci = kc*32 + (lane & 3)*8;
            int iy = iy0 + rr;
            const unsigned short* g = ((unsigned)iy < 128u)
                ? g1b + (((size_t)(b*128) + iy)*128 + px)*128 + ci
                : (const unsigned short*)zsc;      // 16B of zeros (broadcast)
            async16(g, &sm.s.Araw[(rr*130 + s*16 + 1)*32]);
        }
        // B: 4 taps x 128 co x 32 ci = 32 segments; 8 per wave.
        #pragma unroll
        for (int j = 0; j < 8; ++j) {
            int seg = wid*8 + j;              // 0..31
            int tap = seg >> 3, s = seg & 7;
            int co = s*16 + (lane >> 2);
            int ci = kc*32 + (lane & 3)*8;
            const unsigned short* g = wtb + ((size_t)rt_tab[tap]*128 + co)*128 + ci;
            async16(g, &sm.s.B4[(tap*128 + s*16)*32]);
        }
        __syncthreads();   // compiler drains vmcnt before barrier
        #pragma unroll
        for (int tap = 0; tap < 4; ++tap) {
            int rr = tap >> 1, tt = tap & 1;
            short8 af[4], bf[4];
            #pragma unroll
            for (int fm = 0; fm < 4; ++fm)
                af[fm] = *(const short8*)&sm.s.Araw[
                    (rr*130 + wm*64 + fm*16 + l15 + par + tt)*32 + q*8];
            #pragma unroll
            for (int fn = 0; fn < 4; ++fn)
                bf[fn] = *(const short8*)&sm.s.B4[
                    (tap*128 + wn*64 + fn*16 + l15)*32 + q*8];
            #pragma unroll
            for (int fm = 0; fm < 4; ++fm)
                #pragma unroll
                for (int fn = 0; fn < 4; ++fn)
                    acc[fm][fn] = __builtin_amdgcn_mfma_f32_16x16x32_bf16(
                        af[fm], bf[fn], acc[fm][fn], 0, 0, 0);
        }
    }

    // epilogue: GELU(acc + b2), project 128->3, reduce across co in LDS
    float b2v[4];
    float w3v[4][3];
    #pragma unroll
    for (int fn = 0; fn < 4; ++fn) {
        int co = wn*64 + fn*16 + l15;
        b2v[fn] = b2[co];
        w3v[fn][0] = w3[co*3+0]; w3v[fn][1] = w3[co*3+1]; w3v[fn][2] = w3[co*3+2];
    }
    __syncthreads();
    #pragma unroll
    for (int fm = 0; fm < 4; ++fm) {
        #pragma unroll
        for (int rg = 0; rg < 4; ++rg) {
            int px = wm*64 + fm*16 + q*4 + rg;
            float s0 = 0.f, s1 = 0.f, s2 = 0.f;
            #pragma unroll
            for (int fn = 0; fn < 4; ++fn) {
                float y = gelu_f(acc[fm][fn][rg] + b2v[fn]);
                s0 += y*w3v[fn][0]; s1 += y*w3v[fn][1]; s2 += y*w3v[fn][2];
            }
            int slot = wn*16 + l15;
            sm.red[(px*32 + slot)*3 + 0] = s0;
            sm.red[(px*32 + slot)*3 + 1] = s1;
            sm.red[(px*32 + slot)*3 + 2] = s2;
        }
    }
    __syncthreads();
    for (int o = tid; o < 384; o += 256) {
        int px = o/3, jj = o - px*3;
        float s = b3[jj];
        #pragma unroll
        for (int g = 0; g < 32; ++g) s += sm.red[(px*32 + g)*3 + jj];
        xrec[(((size_t)(b*256) + oy)*256 + (par + 2*px))*3 + jj] = s;
    }
}

__global__ void k_zero(float* lacc, float* zsc) {
    if (threadIdx.x == 0) lacc[0] = 0.f;
    if (threadIdx.x < 4) zsc[threadIdx.x] = 0.f;
}

__global__ void k_finalize(const float* __restrict__ loss_acc, float* __restrict__ o) {
    if (threadIdx.x == 0) {
        float v = loss_acc[0] * (1.0f/4194304.0f);
        o[0] = v;
        o[1] = v;
    }
}

extern "C" void kernel_launch(void* const* d_in, const int* in_sizes, int n_in,
                              void* d_out, int out_size, void* d_ws, size_t ws_size,
                              hipStream_t stream) {
    (void)in_sizes; (void)n_in; (void)out_size; (void)ws_size;
    const float* x   = (const float*)d_in[0];
    const float* ew1 = (const float*)d_in[1];
    const float* eb1 = (const float*)d_in[2];
    const float* ew2 = (const float*)d_in[3];
    const float* eb2 = (const float*)d_in[4];
    const float* ew3 = (const float*)d_in[5];
    const float* eb3 = (const float*)d_in[6];
    const float* cb  = (const float*)d_in[7];
    const float* dw1 = (const float*)d_in[8];
    const float* db1 = (const float*)d_in[9];
    const float* dw2 = (const float*)d_in[10];
    const float* db2 = (const float*)d_in[11];
    const float* dw3 = (const float*)d_in[12];
    const float* db3 = (const float*)d_in[13];

    float* ws = (float*)d_ws;
    unsigned short* h1h  = (unsigned short*)(ws);                 // 33,554,432 us
    unsigned short* h1l  = (unsigned short*)(ws + 16777216);      // 33,554,432 us
    float*          h2   = ws + 33554432;                         //  8,388,608 f
    float*          ze   = ws + 41943040;                         //  4,194,304 f
    unsigned short* zqb  = (unsigned short*)(ws + 46137344);      //  4,194,304 us
    unsigned short* we2h = (unsigned short*)(ws + 48234496);      //    262,144 us
    unsigned short* we2l = (unsigned short*)(ws + 48365568);      //    262,144 us
    unsigned short* wd2b = (unsigned short*)(ws + 48496640);      //    262,144 us
    unsigned short* wd1b = (unsigned short*)(ws + 48627712);      //    131,072 us
    float*          lacc = ws + 48693248;                         //          1 f
    float*          zsc  = ws + 48693252;                         //  4 f (16B zeros)
    unsigned short* g1b  = h1h;   // reuse (dead after conv2m)

    float* xrec = (float*)d_out;            // 3,145,728 f
    float* tokf = xrec + 3145728;           //    65,536 f
    float* loss = tokf + 65536;             //         2 f

    k_zero    <<<   1,  64, 0, stream>>>(lacc, zsc);
    k_wsplit2 <<<1024, 256, 0, stream>>>(ew2, we2h, we2l);
    k_wcvt2   <<<1024, 256, 0, stream>>>(dw2, wd2b);
    k_wcvt1   <<< 512, 256, 0, stream>>>(dw1, wd1b);
    k_conv1   <<<4096, 256, 0, stream>>>(x, ew1, eb1, h1h, h1l);
    k_conv2m  <<< 512, 256, 0, stream>>>(h1h, h1l, we2h, we2l, eb2, h2);
    k_conv3   <<< 512, 256, 0, stream>>>(h2, ew3, eb3, ze);
    k_vq      <<<1024, 256, 0, stream>>>(ze, cb, zqb, tokf, lacc);
    k_convt1m <<<4096, 256, 0, stream>>>(zqb, wd1b, db1, g1b);
    k_convt2  <<<8192, 256, 0, stream>>>(g1b, wd2b, db2, dw3, db3, zsc, xrec);
    k_finalize<<<   1,  64, 0, stream>>>(lacc, loss);
}

// Round 6
// 831.078 us; speedup vs baseline: 3.5748x; 1.0440x over previous
//
#include <hip/hip_runtime.h>
#include <math.h>

// Shapes: B=16, x[16,256,256,3], h1[16,128,128,128], h2[16,64,64,128],
// z_e/z_q[65536,64], g1[16,128,128,128](bf16), x_rec[16,256,256,3], K=1024.
//
// R6: convt2: 1-row A + 2-tap B phases (LDS 49.4->24.7 KB, 5 blocks/CU),
// shuffle-reduce epilogue (kills ~5e7 epilogue bank conflicts), XCD swizzle
// (FETCH 262->~80MB). conv2m + convt1m ported to async16 staging (no VGPR
// roundtrip / bounds branches). Decoder gelu -> sigmoid form (token-safe:
// encoder keeps tanhf, tokens bit-identical).

typedef __attribute__((ext_vector_type(8))) short short8;
typedef __attribute__((ext_vector_type(4))) float f32x4;

__device__ __forceinline__ float gelu_f(float x) {          // encoder (exact path)
    float x3 = x*x*x;
    return 0.5f*x*(1.0f + tanhf(0.7978845608028654f*(x + 0.044715f*x3)));
}
__device__ __forceinline__ float gelu_fast(float x) {       // decoder only
    float t = __expf(-1.5957691216057308f*(x + 0.044715f*x*x*x));
    return x / (1.f + t);
}

__device__ __forceinline__ unsigned short f2bf(float f) {
    unsigned int u = __float_as_uint(f);
    u = (u + 0x7FFFu + ((u >> 16) & 1u)) >> 16;   // RNE
    return (unsigned short)u;
}
__device__ __forceinline__ float bf2f(unsigned short h) {
    return __uint_as_float(((unsigned int)h) << 16);
}

typedef const __attribute__((address_space(1))) unsigned int* gp_t;
typedef __attribute__((address_space(3))) unsigned int* lp_t;
__device__ __forceinline__ void async16(const void* g, void* l) {
    __builtin_amdgcn_global_load_lds((gp_t)g, (lp_t)l, 16, 0, 0);
}

// ---------------- conv1: x[16,256,256,3] -> h1 hi/lo bf16 planes, 4x4 s2 SAME, GELU
__global__ __launch_bounds__(256) void k_conv1(const float* __restrict__ x,
        const float* __restrict__ w, const float* __restrict__ bias,
        unsigned short* __restrict__ outh, unsigned short* __restrict__ outl) {
    __shared__ __align__(16) float ws[48*128];
    __shared__ __align__(16) float xs[4][390];
    const int tid = threadIdx.x;
    const int blk = blockIdx.x;
    const int oxt = blk & 1;
    const int oy  = (blk >> 1) & 127;
    const int b   = blk >> 8;
    const int cg = tid & 15, pg = tid >> 4;
    const int c0a = cg*4, c0b = 64 + cg*4;
    const int p0 = pg*4;
    const int ox0 = oxt*64;

    for (int i = tid; i < 6144; i += 256) ws[i] = w[i];
    for (int r = 0; r < 4; ++r) {
        int iy = 2*oy + r - 1;
        bool yok = (unsigned)iy < 256u;
        const float* xrow = x + ((size_t)(b*256) + iy)*256*3;
        for (int i = tid; i < 390; i += 256) {
            int ixl = i/3, ci = i - ixl*3;
            int ix = 2*ox0 - 1 + ixl;
            xs[r][i] = (yok && (unsigned)ix < 256u) ? xrow[(size_t)ix*3 + ci] : 0.f;
        }
    }
    __syncthreads();

    float acc[4][8];
    #pragma unroll
    for (int j = 0; j < 4; ++j)
        #pragma unroll
        for (int i = 0; i < 8; ++i) acc[j][i] = 0.f;

    #pragma unroll 6
    for (int pos = 0; pos < 48; ++pos) {
        int r = pos/12, tc = pos - r*12;
        int t = tc/3,  ci = tc - t*3;
        float4 w0 = *(const float4*)&ws[pos*128 + c0a];
        float4 w1 = *(const float4*)&ws[pos*128 + c0b];
        #pragma unroll
        for (int j = 0; j < 4; ++j) {
            float av = xs[r][(2*(p0+j) + t)*3 + ci];
            acc[j][0] += av*w0.x; acc[j][1] += av*w0.y;
            acc[j][2] += av*w0.z; acc[j][3] += av*w0.w;
            acc[j][4] += av*w1.x; acc[j][5] += av*w1.y;
            acc[j][6] += av*w1.z; acc[j][7] += av*w1.w;
        }
    }
    float bv[8];
    #pragma unroll
    for (int i = 0; i < 4; ++i) { bv[i] = bias[c0a+i]; bv[4+i] = bias[c0b+i]; }
    #pragma unroll
    for (int j = 0; j < 4; ++j) {
        int ox = ox0 + p0 + j;
        size_t base = (((size_t)(b*128) + oy)*128 + ox)*128;
        ushort4 ha, hb, la, lb;
        float y;
        y = gelu_f(acc[j][0]+bv[0]); ha.x = f2bf(y); la.x = f2bf(y - bf2f(ha.x));
        y = gelu_f(acc[j][1]+bv[1]); ha.y = f2bf(y); la.y = f2bf(y - bf2f(ha.y));
        y = gelu_f(acc[j][2]+bv[2]); ha.z = f2bf(y); la.z = f2bf(y - bf2f(ha.z));
        y = gelu_f(acc[j][3]+bv[3]); ha.w = f2bf(y); la.w = f2bf(y - bf2f(ha.w));
        y = gelu_f(acc[j][4]+bv[4]); hb.x = f2bf(y); lb.x = f2bf(y - bf2f(hb.x));
        y = gelu_f(acc[j][5]+bv[5]); hb.y = f2bf(y); lb.y = f2bf(y - bf2f(hb.y));
        y = gelu_f(acc[j][6]+bv[6]); hb.z = f2bf(y); lb.z = f2bf(y - bf2f(hb.z));
        y = gelu_f(acc[j][7]+bv[7]); hb.w = f2bf(y); lb.w = f2bf(y - bf2f(hb.w));
        *(ushort4*)&outh[base + c0a] = ha;
        *(ushort4*)&outh[base + c0b] = hb;
        *(ushort4*)&outl[base + c0a] = la;
        *(ushort4*)&outl[base + c0b] = lb;
    }
}

// ---------------- conv2 (split-bf16 MFMA, async16 staging): h1 -> h2 f32, GELU
__global__ __launch_bounds__(256) void k_conv2m(const unsigned short* __restrict__ h1h,
        const unsigned short* __restrict__ h1l,
        const unsigned short* __restrict__ w2h, const unsigned short* __restrict__ w2l,
        const float* __restrict__ bias, const float* __restrict__ zsc,
        float* __restrict__ out) {
    __shared__ __align__(16) unsigned short Ah[2*128*32];
    __shared__ __align__(16) unsigned short Al[2*128*32];
    __shared__ __align__(16) unsigned short Bh[2*128*32];
    __shared__ __align__(16) unsigned short Bl[2*128*32];
    const int tid = threadIdx.x;
    const int yy = blockIdx.x & 31;
    const int b  = blockIdx.x >> 5;
    const int oy0 = yy*2;
    const int lane = tid & 63, l15 = lane & 15, q = lane >> 4;
    const int wid = tid >> 6, wm = wid >> 1, wn = wid & 1;
    const int psub = lane >> 2;
    const int csub = (lane & 3) * 8;

    f32x4 acc[4][4];
    #pragma unroll
    for (int fm = 0; fm < 4; ++fm)
        #pragma unroll
        for (int fn = 0; fn < 4; ++fn) acc[fm][fn] = (f32x4){0.f,0.f,0.f,0.f};

    for (int tap = 0; tap < 16; ++tap) {
        int r = tap >> 2, t = tap & 3;
        for (int cs = 0; cs < 2; ++cs) {
            __syncthreads();
            #pragma unroll
            for (int j = 0; j < 16; ++j) {
                int id = wid*16 + j;          // 0..63, wave-uniform
                int plane = id >> 4;          // 0 Ah, 1 Al, 2 Bh, 3 Bl
                int kc = (id >> 3) & 1, s2 = id & 7;
                int ci = cs*64 + kc*32 + csub;
                if (plane < 2) {
                    int px = s2*16 + psub;
                    int oyv = oy0 + (px >> 6), ox = px & 63;
                    int iy = 2*oyv + r - 1, ix = 2*ox + t - 1;
                    bool ok = (unsigned)iy < 128u && (unsigned)ix < 128u;
                    const unsigned short* base = plane ? h1l : h1h;
                    const unsigned short* gp = ok
                        ? base + (((size_t)(b*128)+iy)*128+ix)*128 + ci
                        : (const unsigned short*)zsc;
                    async16(gp, (plane ? Al : Ah) + (kc*128 + s2*16)*32);
                } else {
                    int co = s2*16 + psub;
                    const unsigned short* base = (plane == 3) ? w2l : w2h;
                    async16(base + ((size_t)tap*128 + co)*128 + ci,
                            ((plane == 3) ? Bl : Bh) + (kc*128 + s2*16)*32);
                }
            }
            __syncthreads();
            #pragma unroll
            for (int kc = 0; kc < 2; ++kc) {
                short8 ah[4], al[4], bh[4], bl[4];
                #pragma unroll
                for (int fm = 0; fm < 4; ++fm) {
                    int row = (kc*128 + wm*64 + fm*16 + l15)*32 + q*8;
                    ah[fm] = *(const short8*)&Ah[row];
                    al[fm] = *(const short8*)&Al[row];
                }
                #pragma unroll
                for (int fn = 0; fn < 4; ++fn) {
                    int row = (kc*128 + wn*64 + fn*16 + l15)*32 + q*8;
                    bh[fn] = *(const short8*)&Bh[row];
                    bl[fn] = *(const short8*)&Bl[row];
                }
                #pragma unroll
                for (int fm = 0; fm < 4; ++fm)
                    #pragma unroll
                    for (int fn = 0; fn < 4; ++fn) {
                        acc[fm][fn] = __builtin_amdgcn_mfma_f32_16x16x32_bf16(
                            ah[fm], bh[fn], acc[fm][fn], 0, 0, 0);
                        acc[fm][fn] = __builtin_amdgcn_mfma_f32_16x16x32_bf16(
                            al[fm], bh[fn], acc[fm][fn], 0, 0, 0);
                        acc[fm][fn] = __builtin_amdgcn_mfma_f32_16x16x32_bf16(
                            ah[fm], bl[fn], acc[fm][fn], 0, 0, 0);
                    }
            }
        }
    }
    float bv[4];
    #pragma unroll
    for (int fn = 0; fn < 4; ++fn) bv[fn] = bias[wn*64 + fn*16 + l15];
    #pragma unroll
    for (int fm = 0; fm < 4; ++fm)
        #pragma unroll
        for (int rg = 0; rg < 4; ++rg) {
            int px = wm*64 + fm*16 + q*4 + rg;
            int oy = oy0 + (px >> 6), ox = px & 63;
            float* o = out + (((size_t)(b*64) + oy)*64 + ox)*128;
            #pragma unroll
            for (int fn = 0; fn < 4; ++fn)
                o[wn*64 + fn*16 + l15] = gelu_f(acc[fm][fn][rg] + bv[fn]);
        }
}

// ---------------- conv3 (1x1, 128->64, f32): h2 -> z_e [65536,64]
__global__ __launch_bounds__(256) void k_conv3(const float* __restrict__ in,
        const float* __restrict__ w, const float* __restrict__ bias,
        float* __restrict__ out) {
    __shared__ __align__(16) float xs[128*33];
    __shared__ __align__(16) float wb[32*64];
    const int tid = threadIdx.x;
    const size_t pix0 = (size_t)blockIdx.x * 128;
    const int cg = tid & 7, pg = tid >> 3;
    const int c0a = cg*4, c0b = 32 + cg*4;
    const int p0 = pg*4;

    float acc[4][8];
    #pragma unroll
    for (int j = 0; j < 4; ++j)
        #pragma unroll
        for (int i = 0; i < 8; ++i) acc[j][i] = 0.f;

    for (int cs = 0; cs < 4; ++cs) {
        __syncthreads();
        for (int i = tid; i < 4096; i += 256) {
            int p = i >> 5, ci = i & 31;
            xs[p*33 + ci] = in[(pix0 + p)*128 + cs*32 + ci];
        }
        for (int i = tid; i < 2048; i += 256) {
            int ci = i >> 6, c = i & 63;
            wb[i] = w[(size_t)(cs*32 + ci)*64 + c];
        }
        __syncthreads();
        #pragma unroll 8
        for (int ci = 0; ci < 32; ++ci) {
            float a_[4];
            #pragma unroll
            for (int j = 0; j < 4; ++j) a_[j] = xs[(p0+j)*33 + ci];
            float4 b0 = *(const float4*)&wb[ci*64 + c0a];
            float4 b1 = *(const float4*)&wb[ci*64 + c0b];
            #pragma unroll
            for (int j = 0; j < 4; ++j) {
                acc[j][0] += a_[j]*b0.x; acc[j][1] += a_[j]*b0.y;
                acc[j][2] += a_[j]*b0.z; acc[j][3] += a_[j]*b0.w;
                acc[j][4] += a_[j]*b1.x; acc[j][5] += a_[j]*b1.y;
                acc[j][6] += a_[j]*b1.z; acc[j][7] += a_[j]*b1.w;
            }
        }
    }
    #pragma unroll
    for (int j = 0; j < 4; ++j) {
        float* o = out + (pix0 + p0 + j)*64;
        float4 va, vb;
        va.x = acc[j][0]+bias[c0a+0]; va.y = acc[j][1]+bias[c0a+1];
        va.z = acc[j][2]+bias[c0a+2]; va.w = acc[j][3]+bias[c0a+3];
        vb.x = acc[j][4]+bias[c0b+0]; vb.y = acc[j][5]+bias[c0b+1];
        vb.z = acc[j][6]+bias[c0b+2]; vb.w = acc[j][7]+bias[c0b+3];
        *(float4*)&o[c0a] = va;
        *(float4*)&o[c0b] = vb;
    }
}

// ---------------- VQ: f32 (exact), writes z_q as bf16 for the decoder
__global__ __launch_bounds__(256) void k_vq(const float* __restrict__ ze,
        const float* __restrict__ cb, unsigned short* __restrict__ zqb,
        float* __restrict__ tok, float* __restrict__ loss_acc) {
    __shared__ __align__(16) float zs[64*65];
    __shared__ __align__(16) float bt[64*132];
    __shared__ float es[128];
    __shared__ float z2s[64];
    __shared__ float rmin[64*16];
    __shared__ int   ridx[64*16];
    __shared__ int   widx[64];
    __shared__ float wsum[4];
    const int tid = threadIdx.x;
    const size_t tok0 = (size_t)blockIdx.x * 64;
    const int cg = tid & 15, pg = tid >> 4;
    const int k0a = cg*4, k0b = 64 + cg*4;
    const int t0 = pg*4;

    for (int i = tid; i < 4096; i += 256) {
        int tk = i >> 6, d = i & 63;
        zs[tk*65 + d] = ze[(tok0 + tk)*64 + d];
    }
    __syncthreads();
    if (tid < 64) {
        float s = 0.f;
        for (int d = 0; d < 64; ++d) { float v = zs[tid*65 + d]; s += v*v; }
        z2s[tid] = s;
    }

    float bmin[4] = {3.4e38f,3.4e38f,3.4e38f,3.4e38f};
    int   bidx[4] = {0,0,0,0};

    for (int ch = 0; ch < 8; ++ch) {
        __syncthreads();
        for (int i = tid; i < 8192; i += 256) {
            int k = i >> 6, d = i & 63;
            bt[d*132 + k] = cb[((size_t)(ch*128) + k)*64 + d];
        }
        __syncthreads();
        if (tid < 128) {
            float s = 0.f;
            for (int d = 0; d < 64; ++d) { float v = bt[d*132 + tid]; s += v*v; }
            es[tid] = s;
        }
        __syncthreads();
        float acc[4][8];
        #pragma unroll
        for (int j = 0; j < 4; ++j)
            #pragma unroll
            for (int i = 0; i < 8; ++i) acc[j][i] = 0.f;
        #pragma unroll 4
        for (int d = 0; d < 64; ++d) {
            float a_[4];
            #pragma unroll
            for (int j = 0; j < 4; ++j) a_[j] = zs[(t0+j)*65 + d];
            float4 b0 = *(const float4*)&bt[d*132 + k0a];
            float4 b1 = *(const float4*)&bt[d*132 + k0b];
            #pragma unroll
            for (int j = 0; j < 4; ++j) {
                acc[j][0] += a_[j]*b0.x; acc[j][1] += a_[j]*b0.y;
                acc[j][2] += a_[j]*b0.z; acc[j][3] += a_[j]*b0.w;
                acc[j][4] += a_[j]*b1.x; acc[j][5] += a_[j]*b1.y;
                acc[j][6] += a_[j]*b1.z; acc[j][7] += a_[j]*b1.w;
            }
        }
        #pragma unroll
        for (int j = 0; j < 4; ++j) {
            float z2 = z2s[t0+j];
            #pragma unroll
            for (int i = 0; i < 4; ++i) {
                float dist = (z2 + es[k0a+i]) - 2.f*acc[j][i];
                int idx = ch*128 + k0a + i;
                if (dist < bmin[j]) { bmin[j] = dist; bidx[j] = idx; }
            }
            #pragma unroll
            for (int i = 0; i < 4; ++i) {
                float dist = (z2 + es[k0b+i]) - 2.f*acc[j][4+i];
                int idx = ch*128 + k0b + i;
                if (dist < bmin[j]) { bmin[j] = dist; bidx[j] = idx; }
            }
        }
    }
    #pragma unroll
    for (int j = 0; j < 4; ++j) {
        rmin[(t0+j)*16 + cg] = bmin[j];
        ridx[(t0+j)*16 + cg] = bidx[j];
    }
    __syncthreads();
    if (tid < 64) {
        float bv = rmin[tid*16]; int bi = ridx[tid*16];
        for (int g = 1; g < 16; ++g) {
            float v = rmin[tid*16 + g]; int ii = ridx[tid*16 + g];
            if (v < bv || (v == bv && ii < bi)) { bv = v; bi = ii; }
        }
        widx[tid] = bi;
        tok[tok0 + tid] = (float)bi;
    }
    __syncthreads();
    float lsum = 0.f;
    for (int i = tid; i < 4096; i += 256) {
        int tk = i >> 6, d = i & 63;
        float v = cb[(size_t)widx[tk]*64 + d];
        zqb[(tok0 + tk)*64 + d] = f2bf(v);
        float diff = v - zs[tk*65 + d];
        lsum += diff*diff;
    }
    #pragma unroll
    for (int off = 32; off > 0; off >>= 1) lsum += __shfl_down(lsum, off, 64);
    if ((tid & 63) == 0) wsum[tid >> 6] = lsum;
    __syncthreads();
    if (tid == 0) atomicAdd(loss_acc, wsum[0]+wsum[1]+wsum[2]+wsum[3]);
}

// ---------------- weight prep kernels
__global__ __launch_bounds__(256) void k_wsplit2(const float* __restrict__ w,
        unsigned short* __restrict__ hi, unsigned short* __restrict__ lo) {
    int i = blockIdx.x*256 + threadIdx.x;        // 262144
    int rt = i >> 14, rem = i & 16383;
    int co = rem >> 7, ci = rem & 127;
    float v = w[((size_t)rt*128 + ci)*128 + co];
    unsigned short h = f2bf(v);
    hi[i] = h;
    lo[i] = f2bf(v - bf2f(h));
}
__global__ __launch_bounds__(256) void k_wcvt2(const float* __restrict__ w,
        unsigned short* __restrict__ o) {
    int i = blockIdx.x*256 + threadIdx.x;        // 262144
    int rt = i >> 14, rem = i & 16383;
    int co = rem >> 7, ci = rem & 127;
    o[i] = f2bf(w[((size_t)rt*128 + ci)*128 + co]);
}
__global__ __launch_bounds__(256) void k_wcvt1(const float* __restrict__ w,
        unsigned short* __restrict__ o) {
    int i = blockIdx.x*256 + threadIdx.x;        // 131072
    int rt = i >> 13, rem = i & 8191;
    int co = rem >> 6, ci = rem & 63;
    o[i] = f2bf(w[((size_t)rt*64 + ci)*128 + co]);
}

// ---------------- convT1 (bf16 MFMA, async16 staging): zqb -> g1b bf16, GELU
__global__ __launch_bounds__(256) void k_convt1m(const unsigned short* __restrict__ zqb,
        const unsigned short* __restrict__ w1b, const float* __restrict__ bias,
        const float* __restrict__ zsc, unsigned short* __restrict__ out) {
    __shared__ __align__(16) unsigned short A[2*128*32];
    __shared__ __align__(16) unsigned short Bm[2*128*32];
    const int tid = threadIdx.x;
    const int par = blockIdx.x & 1;
    const int ey  = (blockIdx.x >> 1) & 1;
    const int qq  = (blockIdx.x >> 2) & 31;
    const int b   = blockIdx.x >> 7;
    const int q0  = qq*2;
    const int lane = tid & 63, l15 = lane & 15, q = lane >> 4;
    const int wid = tid >> 6, wm = wid >> 1, wn = wid & 1;
    const int psub = lane >> 2;
    const int csub = (lane & 3) * 8;

    f32x4 acc[4][4];
    #pragma unroll
    for (int fm = 0; fm < 4; ++fm)
        #pragma unroll
        for (int fn = 0; fn < 4; ++fn) acc[fm][fn] = (f32x4){0.f,0.f,0.f,0.f};

    for (int tap = 0; tap < 4; ++tap) {
        int rr = tap >> 1, tt = tap & 1;
        int rt = (ey + 2*rr)*4 + (par + 2*tt);
        __syncthreads();
        #pragma unroll
        for (int j = 0; j < 8; ++j) {
            int id = wid*8 + j;               // 0..31, wave-uniform
            int kc = (id >> 3) & 1, s2 = id & 7;
            int ci = kc*32 + csub;
            if (id < 16) {
                int px = s2*16 + psub;
                int qv = q0 + (px >> 6), p = px & 63;
                int iy = qv + ey - 1 + rr, ix = p + par - 1 + tt;
                bool ok = (unsigned)iy < 64u && (unsigned)ix < 64u;
                const unsigned short* gp = ok
                    ? zqb + (((size_t)(b*64)+iy)*64+ix)*64 + ci
                    : (const unsigned short*)zsc;
                async16(gp, A + (kc*128 + s2*16)*32);
            } else {
                int co = s2*16 + psub;
                async16(w1b + ((size_t)rt*128 + co)*64 + ci,
                        Bm + (kc*128 + s2*16)*32);
            }
        }
        __syncthreads();
        #pragma unroll
        for (int kc = 0; kc < 2; ++kc) {
            short8 af[4], bf[4];
            #pragma unroll
            for (int fm = 0; fm < 4; ++fm)
                af[fm] = *(const short8*)&A[(kc*128 + wm*64 + fm*16 + l15)*32 + q*8];
            #pragma unroll
            for (int fn = 0; fn < 4; ++fn)
                bf[fn] = *(const short8*)&Bm[(kc*128 + wn*64 + fn*16 + l15)*32 + q*8];
            #pragma unroll
            for (int fm = 0; fm < 4; ++fm)
                #pragma unroll
                for (int fn = 0; fn < 4; ++fn)
                    acc[fm][fn] = __builtin_amdgcn_mfma_f32_16x16x32_bf16(
                        af[fm], bf[fn], acc[fm][fn], 0, 0, 0);
        }
    }
    float bv[4];
    #pragma unroll
    for (int fn = 0; fn < 4; ++fn) bv[fn] = bias[wn*64 + fn*16 + l15];
    #pragma unroll
    for (int fm = 0; fm < 4; ++fm)
        #pragma unroll
        for (int rg = 0; rg < 4; ++rg) {
            int px = wm*64 + fm*16 + q*4 + rg;
            int qv = q0 + (px >> 6), p = px & 63;
            int oy = 2*qv + ey, ox = par + 2*p;
            unsigned short* o = out + (((size_t)(b*128) + oy)*128 + ox)*128;
            #pragma unroll
            for (int fn = 0; fn < 4; ++fn)
                o[wn*64 + fn*16 + l15] = f2bf(gelu_fast(acc[fm][fn][rg] + bv[fn]));
        }
}

// ---------------- convT2 (bf16 MFMA) + fused final 1x1: g1b -> x_rec
// 1-row A + 2-tap B phases (24.7 KB LDS -> ~5 blocks/CU), shuffle epilogue,
// XCD swizzle for g1b L2 reuse.
__global__ __launch_bounds__(256) void k_convt2(const unsigned short* __restrict__ g1b,
        const unsigned short* __restrict__ wtb, const float* __restrict__ b2,
        const float* __restrict__ w3, const float* __restrict__ b3,
        const float* __restrict__ zsc, float* __restrict__ xrec) {
    union SM {
        struct {
            unsigned short Araw[130*32];     // 8320 B (1 input row + halo cols)
            unsigned short B2[2*128*32];     // 16384 B (2 taps)
        } s;
        float red[128*2*3];                  // 3072 B (epilogue partials)
    };
    __shared__ __align__(16) union SM sm;
    const int tid = threadIdx.x;
    // XCD swizzle: xcd = blk&7 (RR dispatch); per-XCD stream: par fast, then qy.
    const int gblk = blockIdx.x;
    const int xcd = gblk & 7;
    const int s_  = gblk >> 3;                 // 0..1023
    const int par = s_ & 1;
    const int qy  = (s_ >> 1) & 127;
    const int ey  = (s_ >> 8) & 1;
    const int b   = xcd*2 + (s_ >> 9);
    const int oy  = qy*2 + ey;
    const int lane = tid & 63, l15 = lane & 15, q = lane >> 4;
    const int wid = tid >> 6, wm = wid >> 1, wn = wid & 1;
    const int iy0 = qy + ey - 1;
    const int psub = lane >> 2;
    const int csub = (lane & 3) * 8;

    f32x4 acc[4][4];
    #pragma unroll
    for (int fm = 0; fm < 4; ++fm)
        #pragma unroll
        for (int fn = 0; fn < 4; ++fn) acc[fm][fn] = (f32x4){0.f,0.f,0.f,0.f};

    // zero halo cols 0 and 129 once (staging never writes them)
    if (tid < 8) {
        int col = (tid >> 2) ? 129 : 0;
        *(uint4*)&sm.s.Araw[col*32 + (tid & 3)*8] = make_uint4(0,0,0,0);
    }

    int rt_tab[4];
    #pragma unroll
    for (int tap = 0; tap < 4; ++tap) {
        int rr = tap >> 1, tt = tap & 1;
        rt_tab[tap] = (ey + 2*rr)*4 + (par + 2*tt);
    }

    for (int kc = 0; kc < 4; ++kc) {
        for (int ph = 0; ph < 2; ++ph) {       // ph = input row rr; taps {2ph, 2ph+1}
            __syncthreads();                   // protect prior reads (and halo, 1st)
            int iy = iy0 + ph;
            bool yok = (unsigned)iy < 128u;
            const unsigned short* arow =
                g1b + ((size_t)(b*128) + (yok ? iy : 0))*128*128;
            #pragma unroll
            for (int j = 0; j < 6; ++j) {
                int id = wid*6 + j;            // 0..23, wave-uniform
                if (id < 8) {                  // A row: 8 KB
                    int s2 = id;
                    int px = s2*16 + psub;
                    const unsigned short* gp = yok
                        ? arow + px*128 + kc*32 + csub
                        : (const unsigned short*)zsc;
                    async16(gp, &sm.s.Araw[(s2*16 + 1)*32]);
                } else {                       // B 2 taps: 16 KB
                    int idb = id - 8;
                    int tp = idb >> 3, s2 = idb & 7;
                    int rt = rt_tab[ph*2 + tp];
                    int co = s2*16 + psub;
                    async16(wtb + (size_t)rt*16384 + co*128 + kc*32 + csub,
                            &sm.s.B2[(tp*128 + s2*16)*32]);
                }
            }
            __syncthreads();                   // drain (compiler emits vmcnt(0))
            #pragma unroll
            for (int tp = 0; tp < 2; ++tp) {   // tap = ph*2+tp, tt = tp
                short8 af[4], bf[4];
                #pragma unroll
                for (int fm = 0; fm < 4; ++fm)
                    af[fm] = *(const short8*)&sm.s.Araw[
                        (wm*64 + fm*16 + l15 + par + tp)*32 + q*8];
                #pragma unroll
                for (int fn = 0; fn < 4; ++fn)
                    bf[fn] = *(const short8*)&sm.s.B2[
                        (tp*128 + wn*64 + fn*16 + l15)*32 + q*8];
                #pragma unroll
                for (int fm = 0; fm < 4; ++fm)
                    #pragma unroll
                    for (int fn = 0; fn < 4; ++fn)
                        acc[fm][fn] = __builtin_amdgcn_mfma_f32_16x16x32_bf16(
                            af[fm], bf[fn], acc[fm][fn], 0, 0, 0);
            }
        }
    }

    // epilogue: GELU(acc+b2), project 128->3, shuffle-reduce over l15, 2 partials
    float b2v[4];
    float w3v[4][3];
    #pragma unroll
    for (int fn = 0; fn < 4; ++fn) {
        int co = wn*64 + fn*16 + l15;
        b2v[fn] = b2[co];
        w3v[fn][0] = w3[co*3+0]; w3v[fn][1] = w3[co*3+1]; w3v[fn][2] = w3[co*3+2];
    }
    __syncthreads();
    #pragma unroll
    for (int fm = 0; fm < 4; ++fm) {
        #pragma unroll
        for (int rg = 0; rg < 4; ++rg) {
            float s0 = 0.f, s1 = 0.f, s2 = 0.f;
            #pragma unroll
            for (int fn = 0; fn < 4; ++fn) {
                float y = gelu_fast(acc[fm][fn][rg] + b2v[fn]);
                s0 += y*w3v[fn][0]; s1 += y*w3v[fn][1]; s2 += y*w3v[fn][2];
            }
            #pragma unroll
            for (int m = 1; m < 16; m <<= 1) {
                s0 += __shfl_xor(s0, m, 64);
                s1 += __shfl_xor(s1, m, 64);
                s2 += __shfl_xor(s2, m, 64);
            }
            if (l15 == 0) {
                int px = wm*64 + fm*16 + q*4 + rg;
                sm.red[(px*2 + wn)*3 + 0] = s0;
                sm.red[(px*2 + wn)*3 + 1] = s1;
                sm.red[(px*2 + wn)*3 + 2] = s2;
            }
        }
    }
    __syncthreads();
    for (int o = tid; o < 384; o += 256) {
        int px = o/3, jj = o - px*3;
        float s = b3[jj] + sm.red[(px*2 + 0)*3 + jj] + sm.red[(px*2 + 1)*3 + jj];
        xrec[(((size_t)(b*256) + oy)*256 + (par + 2*px))*3 + jj] = s;
    }
}

__global__ void k_zero(float* lacc, float* zsc) {
    if (threadIdx.x == 0) lacc[0] = 0.f;
    if (threadIdx.x < 4) zsc[threadIdx.x] = 0.f;
}

__global__ void k_finalize(const float* __restrict__ loss_acc, float* __restrict__ o) {
    if (threadIdx.x == 0) {
        float v = loss_acc[0] * (1.0f/4194304.0f);
        o[0] = v;
        o[1] = v;
    }
}

extern "C" void kernel_launch(void* const* d_in, const int* in_sizes, int n_in,
                              void* d_out, int out_size, void* d_ws, size_t ws_size,
                              hipStream_t stream) {
    (void)in_sizes; (void)n_in; (void)out_size; (void)ws_size;
    const float* x   = (const float*)d_in[0];
    const float* ew1 = (const float*)d_in[1];
    const float* eb1 = (const float*)d_in[2];
    const float* ew2 = (const float*)d_in[3];
    const float* eb2 = (const float*)d_in[4];
    const float* ew3 = (const float*)d_in[5];
    const float* eb3 = (const float*)d_in[6];
    const float* cb  = (const float*)d_in[7];
    const float* dw1 = (const float*)d_in[8];
    const float* db1 = (const float*)d_in[9];
    const float* dw2 = (const float*)d_in[10];
    const float* db2 = (const float*)d_in[11];
    const float* dw3 = (const float*)d_in[12];
    const float* db3 = (const float*)d_in[13];

    float* ws = (float*)d_ws;
    unsigned short* h1h  = (unsigned short*)(ws);                 // 33,554,432 us
    unsigned short* h1l  = (unsigned short*)(ws + 16777216);      // 33,554,432 us
    float*          h2   = ws + 33554432;                         //  8,388,608 f
    float*          ze   = ws + 41943040;                         //  4,194,304 f
    unsigned short* zqb  = (unsigned short*)(ws + 46137344);      //  4,194,304 us
    unsigned short* we2h = (unsigned short*)(ws + 48234496);      //    262,144 us
    unsigned short* we2l = (unsigned short*)(ws + 48365568);      //    262,144 us
    unsigned short* wd2b = (unsigned short*)(ws + 48496640);      //    262,144 us
    unsigned short* wd1b = (unsigned short*)(ws + 48627712);      //    131,072 us
    float*          lacc = ws + 48693248;                         //          1 f
    float*          zsc  = ws + 48693252;                         //  4 f (16B zeros)
    unsigned short* g1b  = h1h;   // reuse (dead after conv2m)

    float* xrec = (float*)d_out;            // 3,145,728 f
    float* tokf = xrec + 3145728;           //    65,536 f
    float* loss = tokf + 65536;             //         2 f

    k_zero    <<<   1,  64, 0, stream>>>(lacc, zsc);
    k_wsplit2 <<<1024, 256, 0, stream>>>(ew2, we2h, we2l);
    k_wcvt2   <<<1024, 256, 0, stream>>>(dw2, wd2b);
    k_wcvt1   <<< 512, 256, 0, stream>>>(dw1, wd1b);
    k_conv1   <<<4096, 256, 0, stream>>>(x, ew1, eb1, h1h, h1l);
    k_conv2m  <<< 512, 256, 0, stream>>>(h1h, h1l, we2h, we2l, eb2, zsc, h2);
    k_conv3   <<< 512, 256, 0, stream>>>(h2, ew3, eb3, ze);
    k_vq      <<<1024, 256, 0, stream>>>(ze, cb, zqb, tokf, lacc);
    k_convt1m <<<4096, 256, 0, stream>>>(zqb, wd1b, db1, zsc, g1b);
    k_convt2  <<<8192, 256, 0, stream>>>(g1b, wd2b, db2, dw3, db3, zsc, xrec);
    k_finalize<<<   1,  64, 0, stream>>>(lacc, loss);
}